// Round 13
// baseline (295.394 us; speedup 1.0000x reference)
//
#include <hip/hip_runtime.h>
#include <math.h>

#define N_NODES 50000
#define N_EDGES 800000
#define EPS 1e-12f
#define SCAN_NB 196   // ceil(50000/256) node blocks; also bucket count (dst>>8)
#define MAXB 6144     // per-bucket capacity (mean 4082)

typedef __attribute__((ext_vector_type(8))) short bf16x8;
typedef __attribute__((ext_vector_type(4))) float f32x4;

__device__ inline unsigned pk_bf16(float a, float b) {
    unsigned ua = __float_as_uint(a), ub = __float_as_uint(b);
    ua = (ua + 0x7FFFu + ((ua >> 16) & 1u)) >> 16;
    ub = (ub + 0x7FFFu + ((ub >> 16) & 1u)) >> 16;
    return ua | (ub << 16);
}

// global weight-image layouts (weights bf16 + biases fp32)
#define W1OFF 0
#define W2OFF 4096
#define W3OFF 13312
#define RS 144
#define EB1 15616
#define EB2 15872
#define EB3 16128
#define EIMG_B 16192     // also NIMG_B
#define DW1OFF 0
#define DW2OFF 4096
#define DW3OFF 13312
#define DW4OFF 22528
#define DB1 24832
#define DB2 25088
#define DB3 25344
#define DB4 25600
#define DIMG_B 25664

// ---------------- K0: fused prep (blocks 0-2) + node init (blocks 3+) -------
__global__ __launch_bounds__(256) void k_init(
    const float* __restrict__ X, const float* __restrict__ yp,
    float4* __restrict__ px4, float* __restrict__ f,
    const float* __restrict__ ew1, const float* __restrict__ ew2,
    const float* __restrict__ ew3, const float* __restrict__ eb1,
    const float* __restrict__ eb2, const float* __restrict__ eb3,
    const float* __restrict__ nw1, const float* __restrict__ nw2,
    const float* __restrict__ nw3, const float* __restrict__ nb1,
    const float* __restrict__ nb2, const float* __restrict__ nb3,
    const float* __restrict__ dw1, const float* __restrict__ dw2,
    const float* __restrict__ dw3, const float* __restrict__ dw4,
    const float* __restrict__ db1, const float* __restrict__ db2,
    const float* __restrict__ db3, const float* __restrict__ db4,
    char* __restrict__ eimg, char* __restrict__ nimg, char* __restrict__ dimg) {
    const int t = threadIdx.x;
    if (blockIdx.x >= 3) {
        int n = (blockIdx.x - 3) * 256 + t;
        if (n < N_NODES) {
            px4[n] = make_float4(X[n * 6 + 0], X[n * 6 + 1], X[n * 6 + 2], X[n * 6 + 4]);
            f[n] = yp[n];
        }
        return;
    }
    const int n = t & 63, kg = t >> 6;
    const int n3 = t & 15, kg3 = t >> 4;
    if (blockIdx.x == 0) {
        unsigned pk[4];
#pragma unroll
        for (int i = 0; i < 4; i++) {
            int k0 = kg * 8 + i * 2;
            float v0 = (k0 < 9) ? ew1[k0 * 64 + n] : 0.f;
            float v1 = (k0 + 1 < 9) ? ew1[(k0 + 1) * 64 + n] : 0.f;
            pk[i] = pk_bf16(v0, v1);
        }
        *(uint4*)(eimg + W1OFF + n * 64 + kg * 16) = make_uint4(pk[0], pk[1], pk[2], pk[3]);
        unsigned pk2[8];
#pragma unroll
        for (int i = 0; i < 8; i++) {
            int k0 = kg * 16 + i * 2;
            pk2[i] = pk_bf16(ew2[k0 * 64 + n], ew2[(k0 + 1) * 64 + n]);
        }
        *(uint4*)(eimg + W2OFF + n * RS + kg * 32) = make_uint4(pk2[0], pk2[1], pk2[2], pk2[3]);
        *(uint4*)(eimg + W2OFF + n * RS + kg * 32 + 16) = make_uint4(pk2[4], pk2[5], pk2[6], pk2[7]);
        unsigned pk3[2];
#pragma unroll
        for (int i = 0; i < 2; i++) {
            int k0 = kg3 * 4 + i * 2;
            float v0 = (n3 < 3) ? ew3[k0 * 3 + n3] : 0.f;
            float v1 = (n3 < 3) ? ew3[(k0 + 1) * 3 + n3] : 0.f;
            pk3[i] = pk_bf16(v0, v1);
        }
        *(uint2*)(eimg + W3OFF + n3 * RS + kg3 * 8) = make_uint2(pk3[0], pk3[1]);
        if (t < 64) {
            ((float*)(eimg + EB1))[t] = eb1[t];
            ((float*)(eimg + EB2))[t] = eb2[t];
        }
        if (t < 16) ((float*)(eimg + EB3))[t] = (t < 3) ? eb3[t] : 0.f;
    } else if (blockIdx.x == 1) {
        unsigned pk[4];
#pragma unroll
        for (int i = 0; i < 4; i++) {
            int k0 = kg * 8 + i * 2;
            float v0 = (k0 < 5) ? nw1[k0 * 64 + n] : 0.f;
            float v1 = (k0 + 1 < 5) ? nw1[(k0 + 1) * 64 + n] : 0.f;
            pk[i] = pk_bf16(v0, v1);
        }
        *(uint4*)(nimg + W1OFF + n * 64 + kg * 16) = make_uint4(pk[0], pk[1], pk[2], pk[3]);
        unsigned pk2[8];
#pragma unroll
        for (int i = 0; i < 8; i++) {
            int k0 = kg * 16 + i * 2;
            pk2[i] = pk_bf16(nw2[k0 * 64 + n], nw2[(k0 + 1) * 64 + n]);
        }
        *(uint4*)(nimg + W2OFF + n * RS + kg * 32) = make_uint4(pk2[0], pk2[1], pk2[2], pk2[3]);
        *(uint4*)(nimg + W2OFF + n * RS + kg * 32 + 16) = make_uint4(pk2[4], pk2[5], pk2[6], pk2[7]);
        unsigned pk3[2];
#pragma unroll
        for (int i = 0; i < 2; i++) {
            int k0 = kg3 * 4 + i * 2;
            float v0 = (n3 == 0) ? nw3[k0] : 0.f;
            float v1 = (n3 == 0) ? nw3[k0 + 1] : 0.f;
            pk3[i] = pk_bf16(v0, v1);
        }
        *(uint2*)(nimg + W3OFF + n3 * RS + kg3 * 8) = make_uint2(pk3[0], pk3[1]);
        if (t < 64) {
            ((float*)(nimg + EB1))[t] = nb1[t];
            ((float*)(nimg + EB2))[t] = nb2[t];
        }
        if (t < 16) ((float*)(nimg + EB3))[t] = (t == 0) ? nb3[0] : 0.f;
    } else {
        unsigned pk[4];
#pragma unroll
        for (int i = 0; i < 4; i++) {
            int k0 = kg * 8 + i * 2;
            float v0 = (k0 < 5) ? dw1[k0 * 64 + n] : 0.f;
            float v1 = (k0 + 1 < 5) ? dw1[(k0 + 1) * 64 + n] : 0.f;
            pk[i] = pk_bf16(v0, v1);
        }
        *(uint4*)(dimg + DW1OFF + n * 64 + kg * 16) = make_uint4(pk[0], pk[1], pk[2], pk[3]);
        unsigned pk2[8], pk3b[8];
#pragma unroll
        for (int i = 0; i < 8; i++) {
            int k0 = kg * 16 + i * 2;
            pk2[i] = pk_bf16(dw2[k0 * 64 + n], dw2[(k0 + 1) * 64 + n]);
            pk3b[i] = pk_bf16(dw3[k0 * 64 + n], dw3[(k0 + 1) * 64 + n]);
        }
        *(uint4*)(dimg + DW2OFF + n * RS + kg * 32) = make_uint4(pk2[0], pk2[1], pk2[2], pk2[3]);
        *(uint4*)(dimg + DW2OFF + n * RS + kg * 32 + 16) = make_uint4(pk2[4], pk2[5], pk2[6], pk2[7]);
        *(uint4*)(dimg + DW3OFF + n * RS + kg * 32) = make_uint4(pk3b[0], pk3b[1], pk3b[2], pk3b[3]);
        *(uint4*)(dimg + DW3OFF + n * RS + kg * 32 + 16) = make_uint4(pk3b[4], pk3b[5], pk3b[6], pk3b[7]);
        unsigned pk4[2];
#pragma unroll
        for (int i = 0; i < 2; i++) {
            int k0 = kg3 * 4 + i * 2;
            float v0 = (n3 == 0) ? dw4[k0] : 0.f;
            float v1 = (n3 == 0) ? dw4[k0 + 1] : 0.f;
            pk4[i] = pk_bf16(v0, v1);
        }
        *(uint2*)(dimg + DW4OFF + n3 * RS + kg3 * 8) = make_uint2(pk4[0], pk4[1]);
        if (t < 64) {
            ((float*)(dimg + DB1))[t] = db1[t];
            ((float*)(dimg + DB2))[t] = db2[t];
            ((float*)(dimg + DB3))[t] = db3[t];
        }
        if (t < 16) ((float*)(dimg + DB4))[t] = (t == 0) ? db4[0] : 0.f;
    }
}

// ---------------- S1: coarse bucket (dst>>8) ----------------
__global__ __launch_bounds__(256) void k_bucket(const int* __restrict__ edge,
                                                int* __restrict__ btail,
                                                int2* __restrict__ staging) {
    __shared__ int hist[256], loff[256], gbase[256], fill[256];
    __shared__ int2 ebL[2048];
    __shared__ unsigned short bktL[2048];
    const int t = threadIdx.x;
    const int base = blockIdx.x * 2048;
    const int cnt = min(2048, N_EDGES - base);
    hist[t] = 0; fill[t] = 0;
    __syncthreads();

    int2 my[8]; int mb[8];
#pragma unroll
    for (int j = 0; j < 8; j++) {
        int i = base + t + j * 256;
        if (i < N_EDGES) {
            int s = edge[i], d = edge[N_EDGES + i];
            my[j] = make_int2(s, d);
            mb[j] = d >> 8;
            atomicAdd(&hist[mb[j]], 1);
        } else mb[j] = -1;
    }
    __syncthreads();
    int v = hist[t];
    loff[t] = v;
    __syncthreads();
    for (int off = 1; off < 256; off <<= 1) {
        int x = (t >= off) ? loff[t - off] : 0;
        __syncthreads();
        loff[t] += x;
        __syncthreads();
    }
    int ex = loff[t] - v;
    __syncthreads();
    loff[t] = ex;
    if (v > 0) gbase[t] = atomicAdd(&btail[t], v);
    __syncthreads();
#pragma unroll
    for (int j = 0; j < 8; j++) {
        if (mb[j] >= 0) {
            int lp = loff[mb[j]] + atomicAdd(&fill[mb[j]], 1);
            ebL[lp] = my[j];
            bktL[lp] = (unsigned short)mb[j];
        }
    }
    __syncthreads();
    for (int i = t; i < cnt; i += 256) {
        int b = bktL[i];
        int gp = gbase[b] + (i - loff[b]);
        if (gp < MAXB) staging[b * MAXB + gp] = ebL[i];
    }
}

// ---------------- S2: per-bucket fine sort + rowptr + edge init (fused) -----
__global__ __launch_bounds__(256) void k_bsort(const int2* __restrict__ staging,
                                               const int* __restrict__ btail,
                                               const float4* __restrict__ px4,
                                               const float* __restrict__ yp,
                                               int2* __restrict__ sd,
                                               float4* __restrict__ dnrm,
                                               float4* __restrict__ ea,
                                               int* __restrict__ rowptr) {
    __shared__ int hist[256], excl[256], fill[256], sbuf[256];
    __shared__ int2 ebL[MAXB];
    const int b = blockIdx.x, t = threadIdx.x;

    // global exclusive base for this bucket (196-wide scan, per block)
    int bv = (t < SCAN_NB) ? btail[t] : 0;
    sbuf[t] = bv;
    __syncthreads();
    for (int off = 1; off < 256; off <<= 1) {
        int x = (t >= off) ? sbuf[t - off] : 0;
        __syncthreads();
        sbuf[t] += x;
        __syncthreads();
    }
    const int gb = (b == 0) ? 0 : sbuf[b - 1];
    const int size = min(btail[b], MAXB);

    for (int i = t; i < size; i += 256) ebL[i] = staging[b * MAXB + i];
    hist[t] = 0; fill[t] = 0;
    __syncthreads();
    for (int i = t; i < size; i += 256) atomicAdd(&hist[ebL[i].y & 255], 1);
    __syncthreads();
    int v = hist[t];
    sbuf[t] = v;
    __syncthreads();
    for (int off = 1; off < 256; off <<= 1) {
        int x = (t >= off) ? sbuf[t - off] : 0;
        __syncthreads();
        sbuf[t] += x;
        __syncthreads();
    }
    int ex = sbuf[t] - v;
    excl[t] = ex;
    int n = (b << 8) + t;
    if (n < N_NODES) rowptr[n] = gb + ex;
    if (b == SCAN_NB - 1 && t == 0) rowptr[N_NODES] = N_EDGES;
    __syncthreads();
    for (int i = t; i < size; i += 256) {
        int2 v2 = ebL[i];
        int ld = v2.y & 255;
        int pos = excl[ld] + atomicAdd(&fill[ld], 1);
        int gp = gb + pos;
        sd[gp] = v2;  // block-private window: L2-absorbed
        float4 ps = px4[v2.x], pd = px4[v2.y];
        float dx = pd.x - ps.x, dy = pd.y - ps.y, dz = pd.z - ps.z;
        float nrm = sqrtf(dx * dx + dy * dy + dz * dz + EPS);
        dnrm[gp] = make_float4(dx, dy, dz, nrm);
        float fr = yp[v2.y] - yp[v2.x];
        ea[gp] = make_float4(fr * dx, fr * dy, fr * dz, 0.f);
    }
}

// ---------------- K2: edge MLP, W=A swapped, weights/biases from global -----
// LDS = per-wave activation buffers only (36.9 KB) -> 4 blocks/CU.
__global__ __launch_bounds__(256, 4) void k_edge_mlp(
    const int2* __restrict__ sd, const float4* __restrict__ dnrm,
    float4* __restrict__ ea, const float* __restrict__ f,
    const char* __restrict__ eimg) {
    __shared__ __align__(16) char smem[4 * 64 * RS];
    const int t = threadIdx.x;
    const int lane = t & 63, wave = t >> 6;
    const int c = lane & 15, q = lane >> 4;

    char* mybuf = smem + wave * (64 * RS);
    const int e = blockIdx.x * 256 + t;
    int2 SD = sd[e];
    float4 DN = dnrm[e];
    float4 EA = ea[e];
    float fs = f[SD.x], fd = f[SD.y];
    {
        char* row = mybuf + lane * RS;
        *(uint4*)(row) = make_uint4(pk_bf16(DN.x, DN.y), pk_bf16(DN.z, DN.w),
                                    pk_bf16(EA.x, EA.y), pk_bf16(EA.z, fs));
        *(uint4*)(row + 16) = make_uint4(pk_bf16(fd, 0.f), 0u, 0u, 0u);
        *(uint4*)(row + 32) = make_uint4(0u, 0u, 0u, 0u);
        *(uint4*)(row + 48) = make_uint4(0u, 0u, 0u, 0u);
    }
    __syncthreads();

    // weight fragments + biases straight from L2-resident image
    bf16x8 Wa1[4], Wa2[8];
#pragma unroll
    for (int mt = 0; mt < 4; mt++)
        Wa1[mt] = *(const bf16x8*)(eimg + W1OFF + (mt * 16 + c) * 64 + q * 16);
#pragma unroll
    for (int mt = 0; mt < 4; mt++)
#pragma unroll
        for (int ks = 0; ks < 2; ks++)
            Wa2[mt * 2 + ks] =
                *(const bf16x8*)(eimg + W2OFF + (mt * 16 + c) * RS + ks * 64 + q * 16);

#pragma unroll
    for (int nt = 0; nt < 4; nt++) {
        char* rowb = mybuf + (nt * 16 + c) * RS;
        // layer 1
        bf16x8 Eb = *(bf16x8*)(rowb + q * 16);
        f32x4 a1[4];
#pragma unroll
        for (int mt = 0; mt < 4; mt++) {
            float4 bb = *(const float4*)(eimg + EB1 + (mt * 16 + q * 4) * 4);
            a1[mt] = (f32x4){bb.x, bb.y, bb.z, bb.w};
            a1[mt] = __builtin_amdgcn_mfma_f32_16x16x32_bf16(Wa1[mt], Eb, a1[mt], 0, 0, 0);
        }
#pragma unroll
        for (int mt = 0; mt < 4; mt++)
            *(uint2*)(rowb + mt * 32 + q * 8) = make_uint2(
                pk_bf16(fmaxf(a1[mt][0], 0.f), fmaxf(a1[mt][1], 0.f)),
                pk_bf16(fmaxf(a1[mt][2], 0.f), fmaxf(a1[mt][3], 0.f)));
        // layer 2
        bf16x8 H0 = *(bf16x8*)(rowb + q * 16);
        bf16x8 H1 = *(bf16x8*)(rowb + 64 + q * 16);
        f32x4 a2[4];
#pragma unroll
        for (int mt = 0; mt < 4; mt++) {
            float4 bb = *(const float4*)(eimg + EB2 + (mt * 16 + q * 4) * 4);
            a2[mt] = (f32x4){bb.x, bb.y, bb.z, bb.w};
            a2[mt] = __builtin_amdgcn_mfma_f32_16x16x32_bf16(Wa2[mt * 2 + 0], H0, a2[mt], 0, 0, 0);
            a2[mt] = __builtin_amdgcn_mfma_f32_16x16x32_bf16(Wa2[mt * 2 + 1], H1, a2[mt], 0, 0, 0);
        }
#pragma unroll
        for (int mt = 0; mt < 4; mt++)
            *(uint2*)(rowb + mt * 32 + q * 8) = make_uint2(
                pk_bf16(fmaxf(a2[mt][0], 0.f), fmaxf(a2[mt][1], 0.f)),
                pk_bf16(fmaxf(a2[mt][2], 0.f), fmaxf(a2[mt][3], 0.f)));
        // layer 3 (64 -> 3)
        bf16x8 G0 = *(bf16x8*)(rowb + q * 16);
        bf16x8 G1 = *(bf16x8*)(rowb + 64 + q * 16);
        bf16x8 W30 = *(const bf16x8*)(eimg + W3OFF + c * RS + q * 16);
        bf16x8 W31 = *(const bf16x8*)(eimg + W3OFF + c * RS + 64 + q * 16);
        float4 b3 = *(const float4*)(eimg + EB3 + q * 16);
        f32x4 a3 = (f32x4){b3.x, b3.y, b3.z, b3.w};
        a3 = __builtin_amdgcn_mfma_f32_16x16x32_bf16(W30, G0, a3, 0, 0, 0);
        a3 = __builtin_amdgcn_mfma_f32_16x16x32_bf16(W31, G1, a3, 0, 0, 0);
        if (q == 0)
            *(float4*)(rowb + 128) = make_float4(a3[0], a3[1], a3[2], a3[3]);
    }

    float4 o = *(float4*)(mybuf + lane * RS + 128);
    ea[e] = make_float4(EA.x + o.x, EA.y + o.y, EA.z + o.z, 0.f);
}

// ---------------- K3: segment-mean + node MLP (same pattern) ----------------
__global__ __launch_bounds__(256, 2) void k_node_mlp(
    const float4* __restrict__ px4, float* __restrict__ f,
    const float4* __restrict__ ea, const int* __restrict__ rowptr,
    const char* __restrict__ nimg) {
    __shared__ __align__(16) char smem[4 * 64 * RS];
    const int t = threadIdx.x;
    const int lane = t & 63, wave = t >> 6;
    const int c = lane & 15, q = lane >> 4;

    char* mybuf = smem + wave * (64 * RS);
    const int idx = blockIdx.x * 256 + t;
    const int n = (idx < N_NODES) ? idx : (N_NODES - 1);

    int b0 = rowptr[n], b1 = rowptr[n + 1];
    float a0 = 0.f, a1s = 0.f, a2s = 0.f;
    for (int p = b0; p < b1; p++) {
        float4 v = ea[p];
        a0 += v.x; a1s += v.y; a2s += v.z;
    }
    float inv = 1.0f / fmaxf((float)(b1 - b0), 1.0f);
    float4 P = px4[n];
    float fn = f[n];
    {
        char* row = mybuf + lane * RS;
        *(uint4*)(row) = make_uint4(pk_bf16(P.w, fn), pk_bf16(a0 * inv, a1s * inv),
                                    pk_bf16(a2s * inv, 0.f), 0u);
        *(uint4*)(row + 16) = make_uint4(0u, 0u, 0u, 0u);
        *(uint4*)(row + 32) = make_uint4(0u, 0u, 0u, 0u);
        *(uint4*)(row + 48) = make_uint4(0u, 0u, 0u, 0u);
    }
    __syncthreads();

    bf16x8 Wa1[4], Wa2[8];
#pragma unroll
    for (int mt = 0; mt < 4; mt++)
        Wa1[mt] = *(const bf16x8*)(nimg + W1OFF + (mt * 16 + c) * 64 + q * 16);
#pragma unroll
    for (int mt = 0; mt < 4; mt++)
#pragma unroll
        for (int ks = 0; ks < 2; ks++)
            Wa2[mt * 2 + ks] =
                *(const bf16x8*)(nimg + W2OFF + (mt * 16 + c) * RS + ks * 64 + q * 16);

#pragma unroll
    for (int nt = 0; nt < 4; nt++) {
        char* rowb = mybuf + (nt * 16 + c) * RS;
        bf16x8 Eb = *(bf16x8*)(rowb + q * 16);
        f32x4 a1[4];
#pragma unroll
        for (int mt = 0; mt < 4; mt++) {
            float4 bb = *(const float4*)(nimg + EB1 + (mt * 16 + q * 4) * 4);
            a1[mt] = (f32x4){bb.x, bb.y, bb.z, bb.w};
            a1[mt] = __builtin_amdgcn_mfma_f32_16x16x32_bf16(Wa1[mt], Eb, a1[mt], 0, 0, 0);
        }
#pragma unroll
        for (int mt = 0; mt < 4; mt++)
            *(uint2*)(rowb + mt * 32 + q * 8) = make_uint2(
                pk_bf16(fmaxf(a1[mt][0], 0.f), fmaxf(a1[mt][1], 0.f)),
                pk_bf16(fmaxf(a1[mt][2], 0.f), fmaxf(a1[mt][3], 0.f)));
        bf16x8 H0 = *(bf16x8*)(rowb + q * 16);
        bf16x8 H1 = *(bf16x8*)(rowb + 64 + q * 16);
        f32x4 a2[4];
#pragma unroll
        for (int mt = 0; mt < 4; mt++) {
            float4 bb = *(const float4*)(nimg + EB2 + (mt * 16 + q * 4) * 4);
            a2[mt] = (f32x4){bb.x, bb.y, bb.z, bb.w};
            a2[mt] = __builtin_amdgcn_mfma_f32_16x16x32_bf16(Wa2[mt * 2 + 0], H0, a2[mt], 0, 0, 0);
            a2[mt] = __builtin_amdgcn_mfma_f32_16x16x32_bf16(Wa2[mt * 2 + 1], H1, a2[mt], 0, 0, 0);
        }
#pragma unroll
        for (int mt = 0; mt < 4; mt++)
            *(uint2*)(rowb + mt * 32 + q * 8) = make_uint2(
                pk_bf16(fmaxf(a2[mt][0], 0.f), fmaxf(a2[mt][1], 0.f)),
                pk_bf16(fmaxf(a2[mt][2], 0.f), fmaxf(a2[mt][3], 0.f)));
        bf16x8 G0 = *(bf16x8*)(rowb + q * 16);
        bf16x8 G1 = *(bf16x8*)(rowb + 64 + q * 16);
        bf16x8 W30 = *(const bf16x8*)(nimg + W3OFF + c * RS + q * 16);
        bf16x8 W31 = *(const bf16x8*)(nimg + W3OFF + c * RS + 64 + q * 16);
        float4 b3 = *(const float4*)(nimg + EB3 + q * 16);
        f32x4 a3 = (f32x4){b3.x, b3.y, b3.z, b3.w};
        a3 = __builtin_amdgcn_mfma_f32_16x16x32_bf16(W30, G0, a3, 0, 0, 0);
        a3 = __builtin_amdgcn_mfma_f32_16x16x32_bf16(W31, G1, a3, 0, 0, 0);
        if (q == 0) *(float*)(rowb + 128) = a3[0];
    }

    float o = *(float*)(mybuf + lane * RS + 128);
    if (idx < N_NODES) f[n] = fn + o;
}

// ---------------- K4: decoder (same pattern, 4 layers) ----------
__global__ __launch_bounds__(256, 2) void k_decoder(
    const float4* __restrict__ px4, const float* __restrict__ f,
    const float* __restrict__ yp, const char* __restrict__ dimg,
    float* __restrict__ out) {
    __shared__ __align__(16) char smem[4 * 64 * RS];
    const int t = threadIdx.x;
    const int lane = t & 63, wave = t >> 6;
    const int c = lane & 15, q = lane >> 4;

    char* mybuf = smem + wave * (64 * RS);
    const int idx = blockIdx.x * 256 + t;
    const int n = (idx < N_NODES) ? idx : (N_NODES - 1);
    float4 P = px4[n];
    float fn = f[n];
    {
        char* row = mybuf + lane * RS;
        *(uint4*)(row) = make_uint4(pk_bf16(P.x, P.y), pk_bf16(P.z, P.w),
                                    pk_bf16(fn, 0.f), 0u);
        *(uint4*)(row + 16) = make_uint4(0u, 0u, 0u, 0u);
        *(uint4*)(row + 32) = make_uint4(0u, 0u, 0u, 0u);
        *(uint4*)(row + 48) = make_uint4(0u, 0u, 0u, 0u);
    }
    __syncthreads();

    bf16x8 Wa1[4], Wa2[8], Wa3[8];
#pragma unroll
    for (int mt = 0; mt < 4; mt++)
        Wa1[mt] = *(const bf16x8*)(dimg + DW1OFF + (mt * 16 + c) * 64 + q * 16);
#pragma unroll
    for (int mt = 0; mt < 4; mt++)
#pragma unroll
        for (int ks = 0; ks < 2; ks++) {
            Wa2[mt * 2 + ks] =
                *(const bf16x8*)(dimg + DW2OFF + (mt * 16 + c) * RS + ks * 64 + q * 16);
            Wa3[mt * 2 + ks] =
                *(const bf16x8*)(dimg + DW3OFF + (mt * 16 + c) * RS + ks * 64 + q * 16);
        }

#pragma unroll
    for (int nt = 0; nt < 4; nt++) {
        char* rowb = mybuf + (nt * 16 + c) * RS;
        bf16x8 Eb = *(bf16x8*)(rowb + q * 16);
        f32x4 a1[4];
#pragma unroll
        for (int mt = 0; mt < 4; mt++) {
            float4 bb = *(const float4*)(dimg + DB1 + (mt * 16 + q * 4) * 4);
            a1[mt] = (f32x4){bb.x, bb.y, bb.z, bb.w};
            a1[mt] = __builtin_amdgcn_mfma_f32_16x16x32_bf16(Wa1[mt], Eb, a1[mt], 0, 0, 0);
        }
#pragma unroll
        for (int mt = 0; mt < 4; mt++)
            *(uint2*)(rowb + mt * 32 + q * 8) = make_uint2(
                pk_bf16(fmaxf(a1[mt][0], 0.f), fmaxf(a1[mt][1], 0.f)),
                pk_bf16(fmaxf(a1[mt][2], 0.f), fmaxf(a1[mt][3], 0.f)));
        bf16x8 H0 = *(bf16x8*)(rowb + q * 16);
        bf16x8 H1 = *(bf16x8*)(rowb + 64 + q * 16);
        f32x4 a2[4];
#pragma unroll
        for (int mt = 0; mt < 4; mt++) {
            float4 bb = *(const float4*)(dimg + DB2 + (mt * 16 + q * 4) * 4);
            a2[mt] = (f32x4){bb.x, bb.y, bb.z, bb.w};
            a2[mt] = __builtin_amdgcn_mfma_f32_16x16x32_bf16(Wa2[mt * 2 + 0], H0, a2[mt], 0, 0, 0);
            a2[mt] = __builtin_amdgcn_mfma_f32_16x16x32_bf16(Wa2[mt * 2 + 1], H1, a2[mt], 0, 0, 0);
        }
#pragma unroll
        for (int mt = 0; mt < 4; mt++)
            *(uint2*)(rowb + mt * 32 + q * 8) = make_uint2(
                pk_bf16(fmaxf(a2[mt][0], 0.f), fmaxf(a2[mt][1], 0.f)),
                pk_bf16(fmaxf(a2[mt][2], 0.f), fmaxf(a2[mt][3], 0.f)));
        bf16x8 G0 = *(bf16x8*)(rowb + q * 16);
        bf16x8 G1 = *(bf16x8*)(rowb + 64 + q * 16);
        f32x4 a3[4];
#pragma unroll
        for (int mt = 0; mt < 4; mt++) {
            float4 bb = *(const float4*)(dimg + DB3 + (mt * 16 + q * 4) * 4);
            a3[mt] = (f32x4){bb.x, bb.y, bb.z, bb.w};
            a3[mt] = __builtin_amdgcn_mfma_f32_16x16x32_bf16(Wa3[mt * 2 + 0], G0, a3[mt], 0, 0, 0);
            a3[mt] = __builtin_amdgcn_mfma_f32_16x16x32_bf16(Wa3[mt * 2 + 1], G1, a3[mt], 0, 0, 0);
        }
#pragma unroll
        for (int mt = 0; mt < 4; mt++)
            *(uint2*)(rowb + mt * 32 + q * 8) = make_uint2(
                pk_bf16(fmaxf(a3[mt][0], 0.f), fmaxf(a3[mt][1], 0.f)),
                pk_bf16(fmaxf(a3[mt][2], 0.f), fmaxf(a3[mt][3], 0.f)));
        bf16x8 F0 = *(bf16x8*)(rowb + q * 16);
        bf16x8 F1 = *(bf16x8*)(rowb + 64 + q * 16);
        bf16x8 W40 = *(const bf16x8*)(dimg + DW4OFF + c * RS + q * 16);
        bf16x8 W41 = *(const bf16x8*)(dimg + DW4OFF + c * RS + 64 + q * 16);
        float4 b4 = *(const float4*)(dimg + DB4 + q * 16);
        f32x4 a4 = (f32x4){b4.x, b4.y, b4.z, b4.w};
        a4 = __builtin_amdgcn_mfma_f32_16x16x32_bf16(W40, F0, a4, 0, 0, 0);
        a4 = __builtin_amdgcn_mfma_f32_16x16x32_bf16(W41, F1, a4, 0, 0, 0);
        if (q == 0) *(float*)(rowb + 128) = a4[0];
    }

    float o = *(float*)(mybuf + lane * RS + 128);
    if (idx < N_NODES) out[n] = yp[n] + o;
}

extern "C" void kernel_launch(void* const* d_in, const int* in_sizes, int n_in,
                              void* d_out, int out_size, void* d_ws, size_t ws_size,
                              hipStream_t stream) {
    const float* X    = (const float*)d_in[0];
    const float* yp   = (const float*)d_in[1];
    const int*   edge = (const int*)d_in[2];
    const float *ew1 = (const float*)d_in[3],  *eb1 = (const float*)d_in[4];
    const float *ew2 = (const float*)d_in[5],  *eb2 = (const float*)d_in[6];
    const float *ew3 = (const float*)d_in[7],  *eb3 = (const float*)d_in[8];
    const float *nw1 = (const float*)d_in[9],  *nb1 = (const float*)d_in[10];
    const float *nw2 = (const float*)d_in[11], *nb2 = (const float*)d_in[12];
    const float *nw3 = (const float*)d_in[13], *nb3 = (const float*)d_in[14];
    const float *dw1 = (const float*)d_in[15], *db1 = (const float*)d_in[16];
    const float *dw2 = (const float*)d_in[17], *db2 = (const float*)d_in[18];
    const float *dw3 = (const float*)d_in[19], *db3 = (const float*)d_in[20];
    const float *dw4 = (const float*)d_in[21], *db4 = (const float*)d_in[22];
    float* out = (float*)d_out;

    char* p = (char*)d_ws;
    auto carve = [&](size_t bytes) {
        char* r = p;
        p += (bytes + 255) & ~(size_t)255;
        return r;
    };
    int2*   sd      = (int2*)  carve(sizeof(int2)   * N_EDGES);
    float4* dnrm    = (float4*)carve(sizeof(float4) * N_EDGES);
    float4* ea      = (float4*)carve(sizeof(float4) * N_EDGES);
    int2*   staging = (int2*)  carve(sizeof(int2)   * SCAN_NB * MAXB);
    float4* px4     = (float4*)carve(sizeof(float4) * N_NODES);
    float*  f       = (float*) carve(sizeof(float)  * N_NODES);
    int*    rowptr  = (int*)   carve(sizeof(int)    * (N_NODES + 1));
    int*    btail   = (int*)   carve(sizeof(int)    * 256);
    char*   eimg    = (char*)  carve(EIMG_B);
    char*   nimg    = (char*)  carve(EIMG_B);
    char*   dimg    = (char*)  carve(DIMG_B);

    const int nb_n = SCAN_NB;                 // 196
    const int nb_e = (N_EDGES + 255) / 256;   // 3125, exact
    const int nb_b = (N_EDGES + 2047) / 2048; // 391

    hipMemsetAsync(btail, 0, sizeof(int) * 256, stream);
    k_init<<<3 + nb_n, 256, 0, stream>>>(X, yp, px4, f,
                                         ew1, ew2, ew3, eb1, eb2, eb3,
                                         nw1, nw2, nw3, nb1, nb2, nb3,
                                         dw1, dw2, dw3, dw4, db1, db2, db3, db4,
                                         eimg, nimg, dimg);
    k_bucket<<<nb_b, 256, 0, stream>>>(edge, btail, staging);
    k_bsort<<<nb_n, 256, 0, stream>>>(staging, btail, px4, yp,
                                      sd, dnrm, ea, rowptr);

    for (int it = 0; it < 3; ++it) {
        k_edge_mlp<<<nb_e, 256, 0, stream>>>(sd, dnrm, ea, f, eimg);
        k_node_mlp<<<nb_n, 256, 0, stream>>>(px4, f, ea, rowptr, nimg);
    }
    k_decoder<<<nb_n, 256, 0, stream>>>(px4, f, yp, dimg, out);
}

// Round 14
// 291.262 us; speedup vs baseline: 1.0142x; 1.0142x over previous
//
#include <hip/hip_runtime.h>
#include <math.h>

#define N_NODES 50000
#define N_EDGES 800000
#define EPS 1e-12f
#define SCAN_NB 196   // ceil(50000/256) node blocks; also bucket count (dst>>8)
#define MAXB 6144     // per-bucket capacity (mean 4082)

typedef __attribute__((ext_vector_type(8))) short bf16x8;
typedef __attribute__((ext_vector_type(4))) float f32x4;

__device__ inline unsigned pk_bf16(float a, float b) {
    unsigned ua = __float_as_uint(a), ub = __float_as_uint(b);
    ua = (ua + 0x7FFFu + ((ua >> 16) & 1u)) >> 16;
    ub = (ub + 0x7FFFu + ((ub >> 16) & 1u)) >> 16;
    return ua | (ub << 16);
}

// image layouts (weights bf16 + biases fp32)
#define W1OFF 0
#define W2OFF 4096
#define W3OFF 13312
#define RS 144
#define EB1 15616
#define EB2 15872
#define EB3 16128
#define EIMG_B 16192     // also NIMG_B
#define DW1OFF 0
#define DW2OFF 4096
#define DW3OFF 13312
#define DW4OFF 22528
#define DB1 24832
#define DB2 25088
#define DB3 25344
#define DB4 25600
#define DIMG_B 25664

// ---------------- K0: fused prep (blocks 0-2) + node init (blocks 3+) -------
__global__ __launch_bounds__(256) void k_init(
    const float* __restrict__ X, const float* __restrict__ yp,
    float4* __restrict__ px4, float* __restrict__ f,
    const float* __restrict__ ew1, const float* __restrict__ ew2,
    const float* __restrict__ ew3, const float* __restrict__ eb1,
    const float* __restrict__ eb2, const float* __restrict__ eb3,
    const float* __restrict__ nw1, const float* __restrict__ nw2,
    const float* __restrict__ nw3, const float* __restrict__ nb1,
    const float* __restrict__ nb2, const float* __restrict__ nb3,
    const float* __restrict__ dw1, const float* __restrict__ dw2,
    const float* __restrict__ dw3, const float* __restrict__ dw4,
    const float* __restrict__ db1, const float* __restrict__ db2,
    const float* __restrict__ db3, const float* __restrict__ db4,
    char* __restrict__ eimg, char* __restrict__ nimg, char* __restrict__ dimg) {
    const int t = threadIdx.x;
    if (blockIdx.x >= 3) {
        int n = (blockIdx.x - 3) * 256 + t;
        if (n < N_NODES) {
            px4[n] = make_float4(X[n * 6 + 0], X[n * 6 + 1], X[n * 6 + 2], X[n * 6 + 4]);
            f[n] = yp[n];
        }
        return;
    }
    const int n = t & 63, kg = t >> 6;
    const int n3 = t & 15, kg3 = t >> 4;
    if (blockIdx.x == 0) {
        unsigned pk[4];
#pragma unroll
        for (int i = 0; i < 4; i++) {
            int k0 = kg * 8 + i * 2;
            float v0 = (k0 < 9) ? ew1[k0 * 64 + n] : 0.f;
            float v1 = (k0 + 1 < 9) ? ew1[(k0 + 1) * 64 + n] : 0.f;
            pk[i] = pk_bf16(v0, v1);
        }
        *(uint4*)(eimg + W1OFF + n * 64 + kg * 16) = make_uint4(pk[0], pk[1], pk[2], pk[3]);
        unsigned pk2[8];
#pragma unroll
        for (int i = 0; i < 8; i++) {
            int k0 = kg * 16 + i * 2;
            pk2[i] = pk_bf16(ew2[k0 * 64 + n], ew2[(k0 + 1) * 64 + n]);
        }
        *(uint4*)(eimg + W2OFF + n * RS + kg * 32) = make_uint4(pk2[0], pk2[1], pk2[2], pk2[3]);
        *(uint4*)(eimg + W2OFF + n * RS + kg * 32 + 16) = make_uint4(pk2[4], pk2[5], pk2[6], pk2[7]);
        unsigned pk3[2];
#pragma unroll
        for (int i = 0; i < 2; i++) {
            int k0 = kg3 * 4 + i * 2;
            float v0 = (n3 < 3) ? ew3[k0 * 3 + n3] : 0.f;
            float v1 = (n3 < 3) ? ew3[(k0 + 1) * 3 + n3] : 0.f;
            pk3[i] = pk_bf16(v0, v1);
        }
        *(uint2*)(eimg + W3OFF + n3 * RS + kg3 * 8) = make_uint2(pk3[0], pk3[1]);
        if (t < 64) {
            ((float*)(eimg + EB1))[t] = eb1[t];
            ((float*)(eimg + EB2))[t] = eb2[t];
        }
        if (t < 16) ((float*)(eimg + EB3))[t] = (t < 3) ? eb3[t] : 0.f;
    } else if (blockIdx.x == 1) {
        unsigned pk[4];
#pragma unroll
        for (int i = 0; i < 4; i++) {
            int k0 = kg * 8 + i * 2;
            float v0 = (k0 < 5) ? nw1[k0 * 64 + n] : 0.f;
            float v1 = (k0 + 1 < 5) ? nw1[(k0 + 1) * 64 + n] : 0.f;
            pk[i] = pk_bf16(v0, v1);
        }
        *(uint4*)(nimg + W1OFF + n * 64 + kg * 16) = make_uint4(pk[0], pk[1], pk[2], pk[3]);
        unsigned pk2[8];
#pragma unroll
        for (int i = 0; i < 8; i++) {
            int k0 = kg * 16 + i * 2;
            pk2[i] = pk_bf16(nw2[k0 * 64 + n], nw2[(k0 + 1) * 64 + n]);
        }
        *(uint4*)(nimg + W2OFF + n * RS + kg * 32) = make_uint4(pk2[0], pk2[1], pk2[2], pk2[3]);
        *(uint4*)(nimg + W2OFF + n * RS + kg * 32 + 16) = make_uint4(pk2[4], pk2[5], pk2[6], pk2[7]);
        unsigned pk3[2];
#pragma unroll
        for (int i = 0; i < 2; i++) {
            int k0 = kg3 * 4 + i * 2;
            float v0 = (n3 == 0) ? nw3[k0] : 0.f;
            float v1 = (n3 == 0) ? nw3[k0 + 1] : 0.f;
            pk3[i] = pk_bf16(v0, v1);
        }
        *(uint2*)(nimg + W3OFF + n3 * RS + kg3 * 8) = make_uint2(pk3[0], pk3[1]);
        if (t < 64) {
            ((float*)(nimg + EB1))[t] = nb1[t];
            ((float*)(nimg + EB2))[t] = nb2[t];
        }
        if (t < 16) ((float*)(nimg + EB3))[t] = (t == 0) ? nb3[0] : 0.f;
    } else {
        unsigned pk[4];
#pragma unroll
        for (int i = 0; i < 4; i++) {
            int k0 = kg * 8 + i * 2;
            float v0 = (k0 < 5) ? dw1[k0 * 64 + n] : 0.f;
            float v1 = (k0 + 1 < 5) ? dw1[(k0 + 1) * 64 + n] : 0.f;
            pk[i] = pk_bf16(v0, v1);
        }
        *(uint4*)(dimg + DW1OFF + n * 64 + kg * 16) = make_uint4(pk[0], pk[1], pk[2], pk[3]);
        unsigned pk2[8], pk3b[8];
#pragma unroll
        for (int i = 0; i < 8; i++) {
            int k0 = kg * 16 + i * 2;
            pk2[i] = pk_bf16(dw2[k0 * 64 + n], dw2[(k0 + 1) * 64 + n]);
            pk3b[i] = pk_bf16(dw3[k0 * 64 + n], dw3[(k0 + 1) * 64 + n]);
        }
        *(uint4*)(dimg + DW2OFF + n * RS + kg * 32) = make_uint4(pk2[0], pk2[1], pk2[2], pk2[3]);
        *(uint4*)(dimg + DW2OFF + n * RS + kg * 32 + 16) = make_uint4(pk2[4], pk2[5], pk2[6], pk2[7]);
        *(uint4*)(dimg + DW3OFF + n * RS + kg * 32) = make_uint4(pk3b[0], pk3b[1], pk3b[2], pk3b[3]);
        *(uint4*)(dimg + DW3OFF + n * RS + kg * 32 + 16) = make_uint4(pk3b[4], pk3b[5], pk3b[6], pk3b[7]);
        unsigned pk4[2];
#pragma unroll
        for (int i = 0; i < 2; i++) {
            int k0 = kg3 * 4 + i * 2;
            float v0 = (n3 == 0) ? dw4[k0] : 0.f;
            float v1 = (n3 == 0) ? dw4[k0 + 1] : 0.f;
            pk4[i] = pk_bf16(v0, v1);
        }
        *(uint2*)(dimg + DW4OFF + n3 * RS + kg3 * 8) = make_uint2(pk4[0], pk4[1]);
        if (t < 64) {
            ((float*)(dimg + DB1))[t] = db1[t];
            ((float*)(dimg + DB2))[t] = db2[t];
            ((float*)(dimg + DB3))[t] = db3[t];
        }
        if (t < 16) ((float*)(dimg + DB4))[t] = (t == 0) ? db4[0] : 0.f;
    }
}

// ---------------- S1: coarse bucket (dst>>8) ----------------
__global__ __launch_bounds__(256) void k_bucket(const int* __restrict__ edge,
                                                int* __restrict__ btail,
                                                int2* __restrict__ staging) {
    __shared__ int hist[256], loff[256], gbase[256], fill[256];
    __shared__ int2 ebL[2048];
    __shared__ unsigned short bktL[2048];
    const int t = threadIdx.x;
    const int base = blockIdx.x * 2048;
    const int cnt = min(2048, N_EDGES - base);
    hist[t] = 0; fill[t] = 0;
    __syncthreads();

    int2 my[8]; int mb[8];
#pragma unroll
    for (int j = 0; j < 8; j++) {
        int i = base + t + j * 256;
        if (i < N_EDGES) {
            int s = edge[i], d = edge[N_EDGES + i];
            my[j] = make_int2(s, d);
            mb[j] = d >> 8;
            atomicAdd(&hist[mb[j]], 1);
        } else mb[j] = -1;
    }
    __syncthreads();
    int v = hist[t];
    loff[t] = v;
    __syncthreads();
    for (int off = 1; off < 256; off <<= 1) {
        int x = (t >= off) ? loff[t - off] : 0;
        __syncthreads();
        loff[t] += x;
        __syncthreads();
    }
    int ex = loff[t] - v;
    __syncthreads();
    loff[t] = ex;
    if (v > 0) gbase[t] = atomicAdd(&btail[t], v);
    __syncthreads();
#pragma unroll
    for (int j = 0; j < 8; j++) {
        if (mb[j] >= 0) {
            int lp = loff[mb[j]] + atomicAdd(&fill[mb[j]], 1);
            ebL[lp] = my[j];
            bktL[lp] = (unsigned short)mb[j];
        }
    }
    __syncthreads();
    for (int i = t; i < cnt; i += 256) {
        int b = bktL[i];
        int gp = gbase[b] + (i - loff[b]);
        if (gp < MAXB) staging[b * MAXB + gp] = ebL[i];
    }
}

// ---------------- S2: per-bucket fine sort + rowptr + edge init (fused) -----
__global__ __launch_bounds__(256) void k_bsort(const int2* __restrict__ staging,
                                               const int* __restrict__ btail,
                                               const float4* __restrict__ px4,
                                               const float* __restrict__ yp,
                                               int2* __restrict__ sd,
                                               float4* __restrict__ dnrm,
                                               float4* __restrict__ ea,
                                               int* __restrict__ rowptr) {
    __shared__ int hist[256], excl[256], fill[256], sbuf[256];
    __shared__ int2 ebL[MAXB];
    const int b = blockIdx.x, t = threadIdx.x;

    // global exclusive base for this bucket (196-wide scan, per block)
    int bv = (t < SCAN_NB) ? btail[t] : 0;
    sbuf[t] = bv;
    __syncthreads();
    for (int off = 1; off < 256; off <<= 1) {
        int x = (t >= off) ? sbuf[t - off] : 0;
        __syncthreads();
        sbuf[t] += x;
        __syncthreads();
    }
    const int gb = (b == 0) ? 0 : sbuf[b - 1];
    const int size = min(btail[b], MAXB);

    for (int i = t; i < size; i += 256) ebL[i] = staging[b * MAXB + i];
    hist[t] = 0; fill[t] = 0;
    __syncthreads();
    for (int i = t; i < size; i += 256) atomicAdd(&hist[ebL[i].y & 255], 1);
    __syncthreads();
    int v = hist[t];
    sbuf[t] = v;
    __syncthreads();
    for (int off = 1; off < 256; off <<= 1) {
        int x = (t >= off) ? sbuf[t - off] : 0;
        __syncthreads();
        sbuf[t] += x;
        __syncthreads();
    }
    int ex = sbuf[t] - v;
    excl[t] = ex;
    int n = (b << 8) + t;
    if (n < N_NODES) rowptr[n] = gb + ex;
    if (b == SCAN_NB - 1 && t == 0) rowptr[N_NODES] = N_EDGES;
    __syncthreads();
    for (int i = t; i < size; i += 256) {
        int2 v2 = ebL[i];
        int ld = v2.y & 255;
        int pos = excl[ld] + atomicAdd(&fill[ld], 1);
        int gp = gb + pos;
        sd[gp] = v2;  // block-private window: L2-absorbed
        float4 ps = px4[v2.x], pd = px4[v2.y];
        float dx = pd.x - ps.x, dy = pd.y - ps.y, dz = pd.z - ps.z;
        float nrm = sqrtf(dx * dx + dy * dy + dz * dz + EPS);
        dnrm[gp] = make_float4(dx, dy, dz, nrm);
        float fr = yp[v2.y] - yp[v2.x];
        ea[gp] = make_float4(fr * dx, fr * dy, fr * dz, 0.f);
    }
}

// ---------------- K2: edge MLP (R12 version: LDS image, hoisted biases) -----
__global__ __launch_bounds__(256, 2) void k_edge_mlp(
    const int2* __restrict__ sd, const float4* __restrict__ dnrm,
    float4* __restrict__ ea, const float* __restrict__ f,
    const char* __restrict__ eimg) {
    __shared__ __align__(16) char smem[EIMG_B + 4 * 64 * RS];
    const int t = threadIdx.x;
    const int lane = t & 63, wave = t >> 6;
    const int c = lane & 15, q = lane >> 4;

    for (int i = t; i < EIMG_B / 16; i += 256)
        ((uint4*)smem)[i] = ((const uint4*)eimg)[i];

    char* mybuf = smem + EIMG_B + wave * (64 * RS);
    const int e = blockIdx.x * 256 + t;
    int2 SD = sd[e];
    float4 DN = dnrm[e];
    float4 EA = ea[e];
    float fs = f[SD.x], fd = f[SD.y];
    {
        char* row = mybuf + lane * RS;
        *(uint4*)(row) = make_uint4(pk_bf16(DN.x, DN.y), pk_bf16(DN.z, DN.w),
                                    pk_bf16(EA.x, EA.y), pk_bf16(EA.z, fs));
        *(uint4*)(row + 16) = make_uint4(pk_bf16(fd, 0.f), 0u, 0u, 0u);
        *(uint4*)(row + 32) = make_uint4(0u, 0u, 0u, 0u);
        *(uint4*)(row + 48) = make_uint4(0u, 0u, 0u, 0u);
    }
    __syncthreads();

    bf16x8 Wa1[4], Wa2[8], Wa3[2];
#pragma unroll
    for (int mt = 0; mt < 4; mt++)
        Wa1[mt] = *(bf16x8*)(smem + W1OFF + (mt * 16 + c) * 64 + q * 16);
#pragma unroll
    for (int mt = 0; mt < 4; mt++)
#pragma unroll
        for (int ks = 0; ks < 2; ks++)
            Wa2[mt * 2 + ks] =
                *(bf16x8*)(smem + W2OFF + (mt * 16 + c) * RS + ks * 64 + q * 16);
#pragma unroll
    for (int ks = 0; ks < 2; ks++)
        Wa3[ks] = *(bf16x8*)(smem + W3OFF + c * RS + ks * 64 + q * 16);
    float4 b1v[4], b2v[4], b3v;
#pragma unroll
    for (int mt = 0; mt < 4; mt++) {
        b1v[mt] = *(const float4*)(smem + EB1 + (mt * 16 + q * 4) * 4);
        b2v[mt] = *(const float4*)(smem + EB2 + (mt * 16 + q * 4) * 4);
    }
    b3v = *(const float4*)(smem + EB3 + q * 16);

#pragma unroll
    for (int nt = 0; nt < 4; nt++) {
        char* rowb = mybuf + (nt * 16 + c) * RS;
        // layer 1
        bf16x8 Eb = *(bf16x8*)(rowb + q * 16);
        f32x4 a1[4];
#pragma unroll
        for (int mt = 0; mt < 4; mt++) {
            a1[mt] = (f32x4){b1v[mt].x, b1v[mt].y, b1v[mt].z, b1v[mt].w};
            a1[mt] = __builtin_amdgcn_mfma_f32_16x16x32_bf16(Wa1[mt], Eb, a1[mt], 0, 0, 0);
        }
#pragma unroll
        for (int mt = 0; mt < 4; mt++)
            *(uint2*)(rowb + mt * 32 + q * 8) = make_uint2(
                pk_bf16(fmaxf(a1[mt][0], 0.f), fmaxf(a1[mt][1], 0.f)),
                pk_bf16(fmaxf(a1[mt][2], 0.f), fmaxf(a1[mt][3], 0.f)));
        // layer 2
        bf16x8 H0 = *(bf16x8*)(rowb + q * 16);
        bf16x8 H1 = *(bf16x8*)(rowb + 64 + q * 16);
        f32x4 a2[4];
#pragma unroll
        for (int mt = 0; mt < 4; mt++) {
            a2[mt] = (f32x4){b2v[mt].x, b2v[mt].y, b2v[mt].z, b2v[mt].w};
            a2[mt] = __builtin_amdgcn_mfma_f32_16x16x32_bf16(Wa2[mt * 2 + 0], H0, a2[mt], 0, 0, 0);
            a2[mt] = __builtin_amdgcn_mfma_f32_16x16x32_bf16(Wa2[mt * 2 + 1], H1, a2[mt], 0, 0, 0);
        }
#pragma unroll
        for (int mt = 0; mt < 4; mt++)
            *(uint2*)(rowb + mt * 32 + q * 8) = make_uint2(
                pk_bf16(fmaxf(a2[mt][0], 0.f), fmaxf(a2[mt][1], 0.f)),
                pk_bf16(fmaxf(a2[mt][2], 0.f), fmaxf(a2[mt][3], 0.f)));
        // layer 3 (64 -> 3)
        bf16x8 G0 = *(bf16x8*)(rowb + q * 16);
        bf16x8 G1 = *(bf16x8*)(rowb + 64 + q * 16);
        f32x4 a3 = (f32x4){b3v.x, b3v.y, b3v.z, b3v.w};
        a3 = __builtin_amdgcn_mfma_f32_16x16x32_bf16(Wa3[0], G0, a3, 0, 0, 0);
        a3 = __builtin_amdgcn_mfma_f32_16x16x32_bf16(Wa3[1], G1, a3, 0, 0, 0);
        if (q == 0)
            *(float4*)(rowb + 128) = make_float4(a3[0], a3[1], a3[2], a3[3]);
    }

    float4 o = *(float4*)(mybuf + lane * RS + 128);
    ea[e] = make_float4(EA.x + o.x, EA.y + o.y, EA.z + o.z, 0.f);
}

// ---------------- K3: segment-mean + node MLP (R12 version) -----------------
__global__ __launch_bounds__(256, 2) void k_node_mlp(
    const float4* __restrict__ px4, float* __restrict__ f,
    const float4* __restrict__ ea, const int* __restrict__ rowptr,
    const char* __restrict__ nimg) {
    __shared__ __align__(16) char smem[EIMG_B + 4 * 64 * RS];
    const int t = threadIdx.x;
    const int lane = t & 63, wave = t >> 6;
    const int c = lane & 15, q = lane >> 4;

    for (int i = t; i < EIMG_B / 16; i += 256)
        ((uint4*)smem)[i] = ((const uint4*)nimg)[i];

    char* mybuf = smem + EIMG_B + wave * (64 * RS);
    const int idx = blockIdx.x * 256 + t;
    const int n = (idx < N_NODES) ? idx : (N_NODES - 1);

    int b0 = rowptr[n], b1 = rowptr[n + 1];
    float a0 = 0.f, a1s = 0.f, a2s = 0.f;
    for (int p = b0; p < b1; p++) {
        float4 v = ea[p];
        a0 += v.x; a1s += v.y; a2s += v.z;
    }
    float inv = 1.0f / fmaxf((float)(b1 - b0), 1.0f);
    float4 P = px4[n];
    float fn = f[n];
    {
        char* row = mybuf + lane * RS;
        *(uint4*)(row) = make_uint4(pk_bf16(P.w, fn), pk_bf16(a0 * inv, a1s * inv),
                                    pk_bf16(a2s * inv, 0.f), 0u);
        *(uint4*)(row + 16) = make_uint4(0u, 0u, 0u, 0u);
        *(uint4*)(row + 32) = make_uint4(0u, 0u, 0u, 0u);
        *(uint4*)(row + 48) = make_uint4(0u, 0u, 0u, 0u);
    }
    __syncthreads();

    bf16x8 Wa1[4], Wa2[8], Wa3[2];
#pragma unroll
    for (int mt = 0; mt < 4; mt++)
        Wa1[mt] = *(bf16x8*)(smem + W1OFF + (mt * 16 + c) * 64 + q * 16);
#pragma unroll
    for (int mt = 0; mt < 4; mt++)
#pragma unroll
        for (int ks = 0; ks < 2; ks++)
            Wa2[mt * 2 + ks] =
                *(bf16x8*)(smem + W2OFF + (mt * 16 + c) * RS + ks * 64 + q * 16);
#pragma unroll
    for (int ks = 0; ks < 2; ks++)
        Wa3[ks] = *(bf16x8*)(smem + W3OFF + c * RS + ks * 64 + q * 16);
    float4 b1v[4], b2v[4], b3v;
#pragma unroll
    for (int mt = 0; mt < 4; mt++) {
        b1v[mt] = *(const float4*)(smem + EB1 + (mt * 16 + q * 4) * 4);
        b2v[mt] = *(const float4*)(smem + EB2 + (mt * 16 + q * 4) * 4);
    }
    b3v = *(const float4*)(smem + EB3 + q * 16);

#pragma unroll
    for (int nt = 0; nt < 4; nt++) {
        char* rowb = mybuf + (nt * 16 + c) * RS;
        bf16x8 Eb = *(bf16x8*)(rowb + q * 16);
        f32x4 a1v[4];
#pragma unroll
        for (int mt = 0; mt < 4; mt++) {
            a1v[mt] = (f32x4){b1v[mt].x, b1v[mt].y, b1v[mt].z, b1v[mt].w};
            a1v[mt] = __builtin_amdgcn_mfma_f32_16x16x32_bf16(Wa1[mt], Eb, a1v[mt], 0, 0, 0);
        }
#pragma unroll
        for (int mt = 0; mt < 4; mt++)
            *(uint2*)(rowb + mt * 32 + q * 8) = make_uint2(
                pk_bf16(fmaxf(a1v[mt][0], 0.f), fmaxf(a1v[mt][1], 0.f)),
                pk_bf16(fmaxf(a1v[mt][2], 0.f), fmaxf(a1v[mt][3], 0.f)));
        bf16x8 H0 = *(bf16x8*)(rowb + q * 16);
        bf16x8 H1 = *(bf16x8*)(rowb + 64 + q * 16);
        f32x4 a2v[4];
#pragma unroll
        for (int mt = 0; mt < 4; mt++) {
            a2v[mt] = (f32x4){b2v[mt].x, b2v[mt].y, b2v[mt].z, b2v[mt].w};
            a2v[mt] = __builtin_amdgcn_mfma_f32_16x16x32_bf16(Wa2[mt * 2 + 0], H0, a2v[mt], 0, 0, 0);
            a2v[mt] = __builtin_amdgcn_mfma_f32_16x16x32_bf16(Wa2[mt * 2 + 1], H1, a2v[mt], 0, 0, 0);
        }
#pragma unroll
        for (int mt = 0; mt < 4; mt++)
            *(uint2*)(rowb + mt * 32 + q * 8) = make_uint2(
                pk_bf16(fmaxf(a2v[mt][0], 0.f), fmaxf(a2v[mt][1], 0.f)),
                pk_bf16(fmaxf(a2v[mt][2], 0.f), fmaxf(a2v[mt][3], 0.f)));
        bf16x8 G0 = *(bf16x8*)(rowb + q * 16);
        bf16x8 G1 = *(bf16x8*)(rowb + 64 + q * 16);
        f32x4 a3 = (f32x4){b3v.x, b3v.y, b3v.z, b3v.w};
        a3 = __builtin_amdgcn_mfma_f32_16x16x32_bf16(Wa3[0], G0, a3, 0, 0, 0);
        a3 = __builtin_amdgcn_mfma_f32_16x16x32_bf16(Wa3[1], G1, a3, 0, 0, 0);
        if (q == 0) *(float*)(rowb + 128) = a3[0];
    }

    float o = *(float*)(mybuf + lane * RS + 128);
    if (idx < N_NODES) f[n] = fn + o;
}

// ---------------- K4: decoder (R12 version) ----------
__global__ __launch_bounds__(256, 2) void k_decoder(
    const float4* __restrict__ px4, const float* __restrict__ f,
    const float* __restrict__ yp, const char* __restrict__ dimg,
    float* __restrict__ out) {
    __shared__ __align__(16) char smem[DIMG_B + 4 * 64 * RS];
    const int t = threadIdx.x;
    const int lane = t & 63, wave = t >> 6;
    const int c = lane & 15, q = lane >> 4;

    for (int i = t; i < DIMG_B / 16; i += 256)
        ((uint4*)smem)[i] = ((const uint4*)dimg)[i];

    char* mybuf = smem + DIMG_B + wave * (64 * RS);
    const int idx = blockIdx.x * 256 + t;
    const int n = (idx < N_NODES) ? idx : (N_NODES - 1);
    float4 P = px4[n];
    float fn = f[n];
    {
        char* row = mybuf + lane * RS;
        *(uint4*)(row) = make_uint4(pk_bf16(P.x, P.y), pk_bf16(P.z, P.w),
                                    pk_bf16(fn, 0.f), 0u);
        *(uint4*)(row + 16) = make_uint4(0u, 0u, 0u, 0u);
        *(uint4*)(row + 32) = make_uint4(0u, 0u, 0u, 0u);
        *(uint4*)(row + 48) = make_uint4(0u, 0u, 0u, 0u);
    }
    __syncthreads();

    bf16x8 Wa1[4], Wa2[8], Wa3[8], Wa4[2];
#pragma unroll
    for (int mt = 0; mt < 4; mt++)
        Wa1[mt] = *(bf16x8*)(smem + DW1OFF + (mt * 16 + c) * 64 + q * 16);
#pragma unroll
    for (int mt = 0; mt < 4; mt++)
#pragma unroll
        for (int ks = 0; ks < 2; ks++) {
            Wa2[mt * 2 + ks] =
                *(bf16x8*)(smem + DW2OFF + (mt * 16 + c) * RS + ks * 64 + q * 16);
            Wa3[mt * 2 + ks] =
                *(bf16x8*)(smem + DW3OFF + (mt * 16 + c) * RS + ks * 64 + q * 16);
        }
#pragma unroll
    for (int ks = 0; ks < 2; ks++)
        Wa4[ks] = *(bf16x8*)(smem + DW4OFF + c * RS + ks * 64 + q * 16);
    float4 b1v[4], b2v[4], b3v[4], b4v;
#pragma unroll
    for (int mt = 0; mt < 4; mt++) {
        b1v[mt] = *(const float4*)(smem + DB1 + (mt * 16 + q * 4) * 4);
        b2v[mt] = *(const float4*)(smem + DB2 + (mt * 16 + q * 4) * 4);
        b3v[mt] = *(const float4*)(smem + DB3 + (mt * 16 + q * 4) * 4);
    }
    b4v = *(const float4*)(smem + DB4 + q * 16);

#pragma unroll
    for (int nt = 0; nt < 4; nt++) {
        char* rowb = mybuf + (nt * 16 + c) * RS;
        bf16x8 Eb = *(bf16x8*)(rowb + q * 16);
        f32x4 a1v[4];
#pragma unroll
        for (int mt = 0; mt < 4; mt++) {
            a1v[mt] = (f32x4){b1v[mt].x, b1v[mt].y, b1v[mt].z, b1v[mt].w};
            a1v[mt] = __builtin_amdgcn_mfma_f32_16x16x32_bf16(Wa1[mt], Eb, a1v[mt], 0, 0, 0);
        }
#pragma unroll
        for (int mt = 0; mt < 4; mt++)
            *(uint2*)(rowb + mt * 32 + q * 8) = make_uint2(
                pk_bf16(fmaxf(a1v[mt][0], 0.f), fmaxf(a1v[mt][1], 0.f)),
                pk_bf16(fmaxf(a1v[mt][2], 0.f), fmaxf(a1v[mt][3], 0.f)));
        bf16x8 H0 = *(bf16x8*)(rowb + q * 16);
        bf16x8 H1 = *(bf16x8*)(rowb + 64 + q * 16);
        f32x4 a2v[4];
#pragma unroll
        for (int mt = 0; mt < 4; mt++) {
            a2v[mt] = (f32x4){b2v[mt].x, b2v[mt].y, b2v[mt].z, b2v[mt].w};
            a2v[mt] = __builtin_amdgcn_mfma_f32_16x16x32_bf16(Wa2[mt * 2 + 0], H0, a2v[mt], 0, 0, 0);
            a2v[mt] = __builtin_amdgcn_mfma_f32_16x16x32_bf16(Wa2[mt * 2 + 1], H1, a2v[mt], 0, 0, 0);
        }
#pragma unroll
        for (int mt = 0; mt < 4; mt++)
            *(uint2*)(rowb + mt * 32 + q * 8) = make_uint2(
                pk_bf16(fmaxf(a2v[mt][0], 0.f), fmaxf(a2v[mt][1], 0.f)),
                pk_bf16(fmaxf(a2v[mt][2], 0.f), fmaxf(a2v[mt][3], 0.f)));
        bf16x8 G0 = *(bf16x8*)(rowb + q * 16);
        bf16x8 G1 = *(bf16x8*)(rowb + 64 + q * 16);
        f32x4 a3v[4];
#pragma unroll
        for (int mt = 0; mt < 4; mt++) {
            a3v[mt] = (f32x4){b3v[mt].x, b3v[mt].y, b3v[mt].z, b3v[mt].w};
            a3v[mt] = __builtin_amdgcn_mfma_f32_16x16x32_bf16(Wa3[mt * 2 + 0], G0, a3v[mt], 0, 0, 0);
            a3v[mt] = __builtin_amdgcn_mfma_f32_16x16x32_bf16(Wa3[mt * 2 + 1], G1, a3v[mt], 0, 0, 0);
        }
#pragma unroll
        for (int mt = 0; mt < 4; mt++)
            *(uint2*)(rowb + mt * 32 + q * 8) = make_uint2(
                pk_bf16(fmaxf(a3v[mt][0], 0.f), fmaxf(a3v[mt][1], 0.f)),
                pk_bf16(fmaxf(a3v[mt][2], 0.f), fmaxf(a3v[mt][3], 0.f)));
        bf16x8 F0 = *(bf16x8*)(rowb + q * 16);
        bf16x8 F1 = *(bf16x8*)(rowb + 64 + q * 16);
        f32x4 a4 = (f32x4){b4v.x, b4v.y, b4v.z, b4v.w};
        a4 = __builtin_amdgcn_mfma_f32_16x16x32_bf16(Wa4[0], F0, a4, 0, 0, 0);
        a4 = __builtin_amdgcn_mfma_f32_16x16x32_bf16(Wa4[1], F1, a4, 0, 0, 0);
        if (q == 0) *(float*)(rowb + 128) = a4[0];
    }

    float o = *(float*)(mybuf + lane * RS + 128);
    if (idx < N_NODES) out[n] = yp[n] + o;
}

extern "C" void kernel_launch(void* const* d_in, const int* in_sizes, int n_in,
                              void* d_out, int out_size, void* d_ws, size_t ws_size,
                              hipStream_t stream) {
    const float* X    = (const float*)d_in[0];
    const float* yp   = (const float*)d_in[1];
    const int*   edge = (const int*)d_in[2];
    const float *ew1 = (const float*)d_in[3],  *eb1 = (const float*)d_in[4];
    const float *ew2 = (const float*)d_in[5],  *eb2 = (const float*)d_in[6];
    const float *ew3 = (const float*)d_in[7],  *eb3 = (const float*)d_in[8];
    const float *nw1 = (const float*)d_in[9],  *nb1 = (const float*)d_in[10];
    const float *nw2 = (const float*)d_in[11], *nb2 = (const float*)d_in[12];
    const float *nw3 = (const float*)d_in[13], *nb3 = (const float*)d_in[14];
    const float *dw1 = (const float*)d_in[15], *db1 = (const float*)d_in[16];
    const float *dw2 = (const float*)d_in[17], *db2 = (const float*)d_in[18];
    const float *dw3 = (const float*)d_in[19], *db3 = (const float*)d_in[20];
    const float *dw4 = (const float*)d_in[21], *db4 = (const float*)d_in[22];
    float* out = (float*)d_out;

    char* p = (char*)d_ws;
    auto carve = [&](size_t bytes) {
        char* r = p;
        p += (bytes + 255) & ~(size_t)255;
        return r;
    };
    int2*   sd      = (int2*)  carve(sizeof(int2)   * N_EDGES);
    float4* dnrm    = (float4*)carve(sizeof(float4) * N_EDGES);
    float4* ea      = (float4*)carve(sizeof(float4) * N_EDGES);
    int2*   staging = (int2*)  carve(sizeof(int2)   * SCAN_NB * MAXB);
    float4* px4     = (float4*)carve(sizeof(float4) * N_NODES);
    float*  f       = (float*) carve(sizeof(float)  * N_NODES);
    int*    rowptr  = (int*)   carve(sizeof(int)    * (N_NODES + 1));
    int*    btail   = (int*)   carve(sizeof(int)    * 256);
    char*   eimg    = (char*)  carve(EIMG_B);
    char*   nimg    = (char*)  carve(EIMG_B);
    char*   dimg    = (char*)  carve(DIMG_B);

    const int nb_n = SCAN_NB;                 // 196
    const int nb_e = (N_EDGES + 255) / 256;   // 3125, exact
    const int nb_b = (N_EDGES + 2047) / 2048; // 391

    hipMemsetAsync(btail, 0, sizeof(int) * 256, stream);
    k_init<<<3 + nb_n, 256, 0, stream>>>(X, yp, px4, f,
                                         ew1, ew2, ew3, eb1, eb2, eb3,
                                         nw1, nw2, nw3, nb1, nb2, nb3,
                                         dw1, dw2, dw3, dw4, db1, db2, db3, db4,
                                         eimg, nimg, dimg);
    k_bucket<<<nb_b, 256, 0, stream>>>(edge, btail, staging);
    k_bsort<<<nb_n, 256, 0, stream>>>(staging, btail, px4, yp,
                                      sd, dnrm, ea, rowptr);

    for (int it = 0; it < 3; ++it) {
        k_edge_mlp<<<nb_e, 256, 0, stream>>>(sd, dnrm, ea, f, eimg);
        k_node_mlp<<<nb_n, 256, 0, stream>>>(px4, f, ea, rowptr, nimg);
    }
    k_decoder<<<nb_n, 256, 0, stream>>>(px4, f, yp, dimg, out);
}

// Round 15
// 278.090 us; speedup vs baseline: 1.0622x; 1.0474x over previous
//
#include <hip/hip_runtime.h>
#include <math.h>

#define N_NODES 50000
#define N_EDGES 800000
#define EPS 1e-12f
#define SCAN_NB 196   // ceil(50000/256) node blocks; also bucket count (dst>>8)
#define MAXB 6144     // per-bucket capacity (mean 4082)

typedef __attribute__((ext_vector_type(8))) short bf16x8;
typedef __attribute__((ext_vector_type(4))) float f32x4;

__device__ inline unsigned pk_bf16(float a, float b) {
    unsigned ua = __float_as_uint(a), ub = __float_as_uint(b);
    ua = (ua + 0x7FFFu + ((ua >> 16) & 1u)) >> 16;
    ub = (ub + 0x7FFFu + ((ub >> 16) & 1u)) >> 16;
    return ua | (ub << 16);
}

// image layouts (weights bf16 + biases fp32)
#define W1OFF 0
#define W2OFF 4096
#define W3OFF 13312
#define RS 144
#define EB1 15616
#define EB2 15872
#define EB3 16128
#define EIMG_B 16192     // also NIMG_B
#define DW1OFF 0
#define DW2OFF 4096
#define DW3OFF 13312
#define DW4OFF 22528
#define DB1 24832
#define DB2 25088
#define DB3 25344
#define DB4 25600
#define DIMG_B 25664

// ---------------- K0: per-node precompute ----------------
__global__ void k_node_init(const float* __restrict__ X, const float* __restrict__ yp,
                            float4* __restrict__ px4, float* __restrict__ f) {
    int n = blockIdx.x * blockDim.x + threadIdx.x;
    if (n < N_NODES) {
        px4[n] = make_float4(X[n * 6 + 0], X[n * 6 + 1], X[n * 6 + 2], X[n * 6 + 4]);
        f[n] = yp[n];
    }
}

// ---------------- KP: one-shot bf16 weight-image + fp32 bias prep -----------
__global__ __launch_bounds__(256) void k_prep(
    const float* __restrict__ ew1, const float* __restrict__ ew2,
    const float* __restrict__ ew3, const float* __restrict__ eb1,
    const float* __restrict__ eb2, const float* __restrict__ eb3,
    const float* __restrict__ nw1, const float* __restrict__ nw2,
    const float* __restrict__ nw3, const float* __restrict__ nb1,
    const float* __restrict__ nb2, const float* __restrict__ nb3,
    const float* __restrict__ dw1, const float* __restrict__ dw2,
    const float* __restrict__ dw3, const float* __restrict__ dw4,
    const float* __restrict__ db1, const float* __restrict__ db2,
    const float* __restrict__ db3, const float* __restrict__ db4,
    char* __restrict__ eimg, char* __restrict__ nimg, char* __restrict__ dimg) {
    const int t = threadIdx.x;
    const int n = t & 63, kg = t >> 6;
    const int n3 = t & 15, kg3 = t >> 4;
    if (blockIdx.x == 0) {
        unsigned pk[4];
#pragma unroll
        for (int i = 0; i < 4; i++) {
            int k0 = kg * 8 + i * 2;
            float v0 = (k0 < 9) ? ew1[k0 * 64 + n] : 0.f;
            float v1 = (k0 + 1 < 9) ? ew1[(k0 + 1) * 64 + n] : 0.f;
            pk[i] = pk_bf16(v0, v1);
        }
        *(uint4*)(eimg + W1OFF + n * 64 + kg * 16) = make_uint4(pk[0], pk[1], pk[2], pk[3]);
        unsigned pk2[8];
#pragma unroll
        for (int i = 0; i < 8; i++) {
            int k0 = kg * 16 + i * 2;
            pk2[i] = pk_bf16(ew2[k0 * 64 + n], ew2[(k0 + 1) * 64 + n]);
        }
        *(uint4*)(eimg + W2OFF + n * RS + kg * 32) = make_uint4(pk2[0], pk2[1], pk2[2], pk2[3]);
        *(uint4*)(eimg + W2OFF + n * RS + kg * 32 + 16) = make_uint4(pk2[4], pk2[5], pk2[6], pk2[7]);
        unsigned pk3[2];
#pragma unroll
        for (int i = 0; i < 2; i++) {
            int k0 = kg3 * 4 + i * 2;
            float v0 = (n3 < 3) ? ew3[k0 * 3 + n3] : 0.f;
            float v1 = (n3 < 3) ? ew3[(k0 + 1) * 3 + n3] : 0.f;
            pk3[i] = pk_bf16(v0, v1);
        }
        *(uint2*)(eimg + W3OFF + n3 * RS + kg3 * 8) = make_uint2(pk3[0], pk3[1]);
        if (t < 64) {
            ((float*)(eimg + EB1))[t] = eb1[t];
            ((float*)(eimg + EB2))[t] = eb2[t];
        }
        if (t < 16) ((float*)(eimg + EB3))[t] = (t < 3) ? eb3[t] : 0.f;
    } else if (blockIdx.x == 1) {
        unsigned pk[4];
#pragma unroll
        for (int i = 0; i < 4; i++) {
            int k0 = kg * 8 + i * 2;
            float v0 = (k0 < 5) ? nw1[k0 * 64 + n] : 0.f;
            float v1 = (k0 + 1 < 5) ? nw1[(k0 + 1) * 64 + n] : 0.f;
            pk[i] = pk_bf16(v0, v1);
        }
        *(uint4*)(nimg + W1OFF + n * 64 + kg * 16) = make_uint4(pk[0], pk[1], pk[2], pk[3]);
        unsigned pk2[8];
#pragma unroll
        for (int i = 0; i < 8; i++) {
            int k0 = kg * 16 + i * 2;
            pk2[i] = pk_bf16(nw2[k0 * 64 + n], nw2[(k0 + 1) * 64 + n]);
        }
        *(uint4*)(nimg + W2OFF + n * RS + kg * 32) = make_uint4(pk2[0], pk2[1], pk2[2], pk2[3]);
        *(uint4*)(nimg + W2OFF + n * RS + kg * 32 + 16) = make_uint4(pk2[4], pk2[5], pk2[6], pk2[7]);
        unsigned pk3[2];
#pragma unroll
        for (int i = 0; i < 2; i++) {
            int k0 = kg3 * 4 + i * 2;
            float v0 = (n3 == 0) ? nw3[k0] : 0.f;
            float v1 = (n3 == 0) ? nw3[k0 + 1] : 0.f;
            pk3[i] = pk_bf16(v0, v1);
        }
        *(uint2*)(nimg + W3OFF + n3 * RS + kg3 * 8) = make_uint2(pk3[0], pk3[1]);
        if (t < 64) {
            ((float*)(nimg + EB1))[t] = nb1[t];
            ((float*)(nimg + EB2))[t] = nb2[t];
        }
        if (t < 16) ((float*)(nimg + EB3))[t] = (t == 0) ? nb3[0] : 0.f;
    } else {
        unsigned pk[4];
#pragma unroll
        for (int i = 0; i < 4; i++) {
            int k0 = kg * 8 + i * 2;
            float v0 = (k0 < 5) ? dw1[k0 * 64 + n] : 0.f;
            float v1 = (k0 + 1 < 5) ? dw1[(k0 + 1) * 64 + n] : 0.f;
            pk[i] = pk_bf16(v0, v1);
        }
        *(uint4*)(dimg + DW1OFF + n * 64 + kg * 16) = make_uint4(pk[0], pk[1], pk[2], pk[3]);
        unsigned pk2[8], pk3b[8];
#pragma unroll
        for (int i = 0; i < 8; i++) {
            int k0 = kg * 16 + i * 2;
            pk2[i] = pk_bf16(dw2[k0 * 64 + n], dw2[(k0 + 1) * 64 + n]);
            pk3b[i] = pk_bf16(dw3[k0 * 64 + n], dw3[(k0 + 1) * 64 + n]);
        }
        *(uint4*)(dimg + DW2OFF + n * RS + kg * 32) = make_uint4(pk2[0], pk2[1], pk2[2], pk2[3]);
        *(uint4*)(dimg + DW2OFF + n * RS + kg * 32 + 16) = make_uint4(pk2[4], pk2[5], pk2[6], pk2[7]);
        *(uint4*)(dimg + DW3OFF + n * RS + kg * 32) = make_uint4(pk3b[0], pk3b[1], pk3b[2], pk3b[3]);
        *(uint4*)(dimg + DW3OFF + n * RS + kg * 32 + 16) = make_uint4(pk3b[4], pk3b[5], pk3b[6], pk3b[7]);
        unsigned pk4[2];
#pragma unroll
        for (int i = 0; i < 2; i++) {
            int k0 = kg3 * 4 + i * 2;
            float v0 = (n3 == 0) ? dw4[k0] : 0.f;
            float v1 = (n3 == 0) ? dw4[k0 + 1] : 0.f;
            pk4[i] = pk_bf16(v0, v1);
        }
        *(uint2*)(dimg + DW4OFF + n3 * RS + kg3 * 8) = make_uint2(pk4[0], pk4[1]);
        if (t < 64) {
            ((float*)(dimg + DB1))[t] = db1[t];
            ((float*)(dimg + DB2))[t] = db2[t];
            ((float*)(dimg + DB3))[t] = db3[t];
        }
        if (t < 16) ((float*)(dimg + DB4))[t] = (t == 0) ? db4[0] : 0.f;
    }
}

// ---------------- S1: coarse bucket (dst>>8) ----------------
__global__ __launch_bounds__(256) void k_bucket(const int* __restrict__ edge,
                                                int* __restrict__ btail,
                                                int2* __restrict__ staging) {
    __shared__ int hist[256], loff[256], gbase[256], fill[256];
    __shared__ int2 ebL[2048];
    __shared__ unsigned short bktL[2048];
    const int t = threadIdx.x;
    const int base = blockIdx.x * 2048;
    const int cnt = min(2048, N_EDGES - base);
    hist[t] = 0; fill[t] = 0;
    __syncthreads();

    int2 my[8]; int mb[8];
#pragma unroll
    for (int j = 0; j < 8; j++) {
        int i = base + t + j * 256;
        if (i < N_EDGES) {
            int s = edge[i], d = edge[N_EDGES + i];
            my[j] = make_int2(s, d);
            mb[j] = d >> 8;
            atomicAdd(&hist[mb[j]], 1);
        } else mb[j] = -1;
    }
    __syncthreads();
    int v = hist[t];
    loff[t] = v;
    __syncthreads();
    for (int off = 1; off < 256; off <<= 1) {
        int x = (t >= off) ? loff[t - off] : 0;
        __syncthreads();
        loff[t] += x;
        __syncthreads();
    }
    int ex = loff[t] - v;
    __syncthreads();
    loff[t] = ex;
    if (v > 0) gbase[t] = atomicAdd(&btail[t], v);
    __syncthreads();
#pragma unroll
    for (int j = 0; j < 8; j++) {
        if (mb[j] >= 0) {
            int lp = loff[mb[j]] + atomicAdd(&fill[mb[j]], 1);
            ebL[lp] = my[j];
            bktL[lp] = (unsigned short)mb[j];
        }
    }
    __syncthreads();
    for (int i = t; i < cnt; i += 256) {
        int b = bktL[i];
        int gp = gbase[b] + (i - loff[b]);
        if (gp < MAXB) staging[b * MAXB + gp] = ebL[i];
    }
}

// ---------------- S2: exclusive scan of bucket sizes ----------------
__global__ void k_bscan(const int* __restrict__ btail, int* __restrict__ bbase) {
    __shared__ int s[256];
    int t = threadIdx.x;
    int v = (t < SCAN_NB) ? btail[t] : 0;
    s[t] = v;
    __syncthreads();
    for (int off = 1; off < 256; off <<= 1) {
        int x = (t >= off) ? s[t - off] : 0;
        __syncthreads();
        s[t] += x;
        __syncthreads();
    }
    if (t < SCAN_NB) bbase[t] = s[t] - v;
}

// ---------------- S3: per-bucket fine sort -> sd + rowptr ----------------
__global__ __launch_bounds__(256) void k_bsort(const int2* __restrict__ staging,
                                               const int* __restrict__ btail,
                                               const int* __restrict__ bbase,
                                               int2* __restrict__ sd,
                                               int* __restrict__ rowptr) {
    __shared__ int hist[256], excl[256], fill[256], sbuf[256];
    __shared__ int2 ebL[MAXB];
    const int b = blockIdx.x, t = threadIdx.x;
    const int size = min(btail[b], MAXB);
    const int gb = bbase[b];
    for (int i = t; i < size; i += 256) ebL[i] = staging[b * MAXB + i];
    hist[t] = 0; fill[t] = 0;
    __syncthreads();
    for (int i = t; i < size; i += 256) atomicAdd(&hist[ebL[i].y & 255], 1);
    __syncthreads();
    int v = hist[t];
    sbuf[t] = v;
    __syncthreads();
    for (int off = 1; off < 256; off <<= 1) {
        int x = (t >= off) ? sbuf[t - off] : 0;
        __syncthreads();
        sbuf[t] += x;
        __syncthreads();
    }
    int ex = sbuf[t] - v;
    excl[t] = ex;
    int n = (b << 8) + t;
    if (n < N_NODES) rowptr[n] = gb + ex;
    if (b == SCAN_NB - 1 && t == 0) rowptr[N_NODES] = N_EDGES;
    __syncthreads();
    for (int i = t; i < size; i += 256) {
        int2 v2 = ebL[i];
        int ld = v2.y & 255;
        int pos = excl[ld] + atomicAdd(&fill[ld], 1);
        sd[gb + pos] = v2;
    }
}

// ---------------- K1: per-edge precompute (sorted order) --------
__global__ void k_edge_init(const int2* __restrict__ sd,
                            const float4* __restrict__ px4,
                            const float* __restrict__ yp,
                            float4* __restrict__ dnrm, float4* __restrict__ ea) {
    int e = blockIdx.x * blockDim.x + threadIdx.x;
    if (e < N_EDGES) {
        int2 SD = sd[e];
        float4 ps = px4[SD.x], pd = px4[SD.y];
        float dx = pd.x - ps.x, dy = pd.y - ps.y, dz = pd.z - ps.z;
        float nrm = sqrtf(dx * dx + dy * dy + dz * dz + EPS);
        dnrm[e] = make_float4(dx, dy, dz, nrm);
        float fr = yp[SD.y] - yp[SD.x];
        ea[e] = make_float4(fr * dx, fr * dy, fr * dz, 0.f);
    }
}

// ---------------- K2: edge MLP, W=A swapped, hoisted GLOBAL weights ---------
// No LDS weight image: LDS = activation buffers only (36.9 KB) -> 3 blocks/CU.
__global__ __launch_bounds__(256, 3) void k_edge_mlp(
    const int2* __restrict__ sd, const float4* __restrict__ dnrm,
    float4* __restrict__ ea, const float* __restrict__ f,
    const char* __restrict__ eimg) {
    __shared__ __align__(16) char smem[4 * 64 * RS];
    const int t = threadIdx.x;
    const int lane = t & 63, wave = t >> 6;
    const int c = lane & 15, q = lane >> 4;

    char* mybuf = smem + wave * (64 * RS);
    const int e = blockIdx.x * 256 + t;
    int2 SD = sd[e];
    float4 DN = dnrm[e];
    float4 EA = ea[e];
    float fs = f[SD.x], fd = f[SD.y];

    // hoisted weight fragments + biases from L2-resident image (once per thread)
    bf16x8 Wa1[4], Wa2[8], Wa3[2];
#pragma unroll
    for (int mt = 0; mt < 4; mt++)
        Wa1[mt] = *(const bf16x8*)(eimg + W1OFF + (mt * 16 + c) * 64 + q * 16);
#pragma unroll
    for (int mt = 0; mt < 4; mt++)
#pragma unroll
        for (int ks = 0; ks < 2; ks++)
            Wa2[mt * 2 + ks] =
                *(const bf16x8*)(eimg + W2OFF + (mt * 16 + c) * RS + ks * 64 + q * 16);
#pragma unroll
    for (int ks = 0; ks < 2; ks++)
        Wa3[ks] = *(const bf16x8*)(eimg + W3OFF + c * RS + ks * 64 + q * 16);
    float4 b1v[4], b2v[4], b3v;
#pragma unroll
    for (int mt = 0; mt < 4; mt++) {
        b1v[mt] = *(const float4*)(eimg + EB1 + (mt * 16 + q * 4) * 4);
        b2v[mt] = *(const float4*)(eimg + EB2 + (mt * 16 + q * 4) * 4);
    }
    b3v = *(const float4*)(eimg + EB3 + q * 16);

    {
        char* row = mybuf + lane * RS;
        *(uint4*)(row) = make_uint4(pk_bf16(DN.x, DN.y), pk_bf16(DN.z, DN.w),
                                    pk_bf16(EA.x, EA.y), pk_bf16(EA.z, fs));
        *(uint4*)(row + 16) = make_uint4(pk_bf16(fd, 0.f), 0u, 0u, 0u);
        *(uint4*)(row + 32) = make_uint4(0u, 0u, 0u, 0u);
        *(uint4*)(row + 48) = make_uint4(0u, 0u, 0u, 0u);
    }
    __syncthreads();

#pragma unroll
    for (int nt = 0; nt < 4; nt++) {
        char* rowb = mybuf + (nt * 16 + c) * RS;
        // layer 1
        bf16x8 Eb = *(bf16x8*)(rowb + q * 16);
        f32x4 a1[4];
#pragma unroll
        for (int mt = 0; mt < 4; mt++) {
            a1[mt] = (f32x4){b1v[mt].x, b1v[mt].y, b1v[mt].z, b1v[mt].w};
            a1[mt] = __builtin_amdgcn_mfma_f32_16x16x32_bf16(Wa1[mt], Eb, a1[mt], 0, 0, 0);
        }
#pragma unroll
        for (int mt = 0; mt < 4; mt++)
            *(uint2*)(rowb + mt * 32 + q * 8) = make_uint2(
                pk_bf16(fmaxf(a1[mt][0], 0.f), fmaxf(a1[mt][1], 0.f)),
                pk_bf16(fmaxf(a1[mt][2], 0.f), fmaxf(a1[mt][3], 0.f)));
        // layer 2
        bf16x8 H0 = *(bf16x8*)(rowb + q * 16);
        bf16x8 H1 = *(bf16x8*)(rowb + 64 + q * 16);
        f32x4 a2[4];
#pragma unroll
        for (int mt = 0; mt < 4; mt++) {
            a2[mt] = (f32x4){b2v[mt].x, b2v[mt].y, b2v[mt].z, b2v[mt].w};
            a2[mt] = __builtin_amdgcn_mfma_f32_16x16x32_bf16(Wa2[mt * 2 + 0], H0, a2[mt], 0, 0, 0);
            a2[mt] = __builtin_amdgcn_mfma_f32_16x16x32_bf16(Wa2[mt * 2 + 1], H1, a2[mt], 0, 0, 0);
        }
#pragma unroll
        for (int mt = 0; mt < 4; mt++)
            *(uint2*)(rowb + mt * 32 + q * 8) = make_uint2(
                pk_bf16(fmaxf(a2[mt][0], 0.f), fmaxf(a2[mt][1], 0.f)),
                pk_bf16(fmaxf(a2[mt][2], 0.f), fmaxf(a2[mt][3], 0.f)));
        // layer 3 (64 -> 3)
        bf16x8 G0 = *(bf16x8*)(rowb + q * 16);
        bf16x8 G1 = *(bf16x8*)(rowb + 64 + q * 16);
        f32x4 a3 = (f32x4){b3v.x, b3v.y, b3v.z, b3v.w};
        a3 = __builtin_amdgcn_mfma_f32_16x16x32_bf16(Wa3[0], G0, a3, 0, 0, 0);
        a3 = __builtin_amdgcn_mfma_f32_16x16x32_bf16(Wa3[1], G1, a3, 0, 0, 0);
        if (q == 0)
            *(float4*)(rowb + 128) = make_float4(a3[0], a3[1], a3[2], a3[3]);
    }

    float4 o = *(float4*)(mybuf + lane * RS + 128);
    ea[e] = make_float4(EA.x + o.x, EA.y + o.y, EA.z + o.z, 0.f);
}

// ---------------- K3: segment-mean + node MLP (R12 version) -----------------
__global__ __launch_bounds__(256, 2) void k_node_mlp(
    const float4* __restrict__ px4, float* __restrict__ f,
    const float4* __restrict__ ea, const int* __restrict__ rowptr,
    const char* __restrict__ nimg) {
    __shared__ __align__(16) char smem[EIMG_B + 4 * 64 * RS];
    const int t = threadIdx.x;
    const int lane = t & 63, wave = t >> 6;
    const int c = lane & 15, q = lane >> 4;

    for (int i = t; i < EIMG_B / 16; i += 256)
        ((uint4*)smem)[i] = ((const uint4*)nimg)[i];

    char* mybuf = smem + EIMG_B + wave * (64 * RS);
    const int idx = blockIdx.x * 256 + t;
    const int n = (idx < N_NODES) ? idx : (N_NODES - 1);

    int b0 = rowptr[n], b1 = rowptr[n + 1];
    float a0 = 0.f, a1s = 0.f, a2s = 0.f;
    for (int p = b0; p < b1; p++) {
        float4 v = ea[p];
        a0 += v.x; a1s += v.y; a2s += v.z;
    }
    float inv = 1.0f / fmaxf((float)(b1 - b0), 1.0f);
    float4 P = px4[n];
    float fn = f[n];
    {
        char* row = mybuf + lane * RS;
        *(uint4*)(row) = make_uint4(pk_bf16(P.w, fn), pk_bf16(a0 * inv, a1s * inv),
                                    pk_bf16(a2s * inv, 0.f), 0u);
        *(uint4*)(row + 16) = make_uint4(0u, 0u, 0u, 0u);
        *(uint4*)(row + 32) = make_uint4(0u, 0u, 0u, 0u);
        *(uint4*)(row + 48) = make_uint4(0u, 0u, 0u, 0u);
    }
    __syncthreads();

    bf16x8 Wa1[4], Wa2[8], Wa3[2];
#pragma unroll
    for (int mt = 0; mt < 4; mt++)
        Wa1[mt] = *(bf16x8*)(smem + W1OFF + (mt * 16 + c) * 64 + q * 16);
#pragma unroll
    for (int mt = 0; mt < 4; mt++)
#pragma unroll
        for (int ks = 0; ks < 2; ks++)
            Wa2[mt * 2 + ks] =
                *(bf16x8*)(smem + W2OFF + (mt * 16 + c) * RS + ks * 64 + q * 16);
#pragma unroll
    for (int ks = 0; ks < 2; ks++)
        Wa3[ks] = *(bf16x8*)(smem + W3OFF + c * RS + ks * 64 + q * 16);
    float4 b1v[4], b2v[4], b3v;
#pragma unroll
    for (int mt = 0; mt < 4; mt++) {
        b1v[mt] = *(const float4*)(smem + EB1 + (mt * 16 + q * 4) * 4);
        b2v[mt] = *(const float4*)(smem + EB2 + (mt * 16 + q * 4) * 4);
    }
    b3v = *(const float4*)(smem + EB3 + q * 16);

#pragma unroll
    for (int nt = 0; nt < 4; nt++) {
        char* rowb = mybuf + (nt * 16 + c) * RS;
        bf16x8 Eb = *(bf16x8*)(rowb + q * 16);
        f32x4 a1v[4];
#pragma unroll
        for (int mt = 0; mt < 4; mt++) {
            a1v[mt] = (f32x4){b1v[mt].x, b1v[mt].y, b1v[mt].z, b1v[mt].w};
            a1v[mt] = __builtin_amdgcn_mfma_f32_16x16x32_bf16(Wa1[mt], Eb, a1v[mt], 0, 0, 0);
        }
#pragma unroll
        for (int mt = 0; mt < 4; mt++)
            *(uint2*)(rowb + mt * 32 + q * 8) = make_uint2(
                pk_bf16(fmaxf(a1v[mt][0], 0.f), fmaxf(a1v[mt][1], 0.f)),
                pk_bf16(fmaxf(a1v[mt][2], 0.f), fmaxf(a1v[mt][3], 0.f)));
        bf16x8 H0 = *(bf16x8*)(rowb + q * 16);
        bf16x8 H1 = *(bf16x8*)(rowb + 64 + q * 16);
        f32x4 a2v[4];
#pragma unroll
        for (int mt = 0; mt < 4; mt++) {
            a2v[mt] = (f32x4){b2v[mt].x, b2v[mt].y, b2v[mt].z, b2v[mt].w};
            a2v[mt] = __builtin_amdgcn_mfma_f32_16x16x32_bf16(Wa2[mt * 2 + 0], H0, a2v[mt], 0, 0, 0);
            a2v[mt] = __builtin_amdgcn_mfma_f32_16x16x32_bf16(Wa2[mt * 2 + 1], H1, a2v[mt], 0, 0, 0);
        }
#pragma unroll
        for (int mt = 0; mt < 4; mt++)
            *(uint2*)(rowb + mt * 32 + q * 8) = make_uint2(
                pk_bf16(fmaxf(a2v[mt][0], 0.f), fmaxf(a2v[mt][1], 0.f)),
                pk_bf16(fmaxf(a2v[mt][2], 0.f), fmaxf(a2v[mt][3], 0.f)));
        bf16x8 G0 = *(bf16x8*)(rowb + q * 16);
        bf16x8 G1 = *(bf16x8*)(rowb + 64 + q * 16);
        f32x4 a3 = (f32x4){b3v.x, b3v.y, b3v.z, b3v.w};
        a3 = __builtin_amdgcn_mfma_f32_16x16x32_bf16(Wa3[0], G0, a3, 0, 0, 0);
        a3 = __builtin_amdgcn_mfma_f32_16x16x32_bf16(Wa3[1], G1, a3, 0, 0, 0);
        if (q == 0) *(float*)(rowb + 128) = a3[0];
    }

    float o = *(float*)(mybuf + lane * RS + 128);
    if (idx < N_NODES) f[n] = fn + o;
}

// ---------------- K4: decoder (R12 version) ----------
__global__ __launch_bounds__(256, 2) void k_decoder(
    const float4* __restrict__ px4, const float* __restrict__ f,
    const float* __restrict__ yp, const char* __restrict__ dimg,
    float* __restrict__ out) {
    __shared__ __align__(16) char smem[DIMG_B + 4 * 64 * RS];
    const int t = threadIdx.x;
    const int lane = t & 63, wave = t >> 6;
    const int c = lane & 15, q = lane >> 4;

    for (int i = t; i < DIMG_B / 16; i += 256)
        ((uint4*)smem)[i] = ((const uint4*)dimg)[i];

    char* mybuf = smem + DIMG_B + wave * (64 * RS);
    const int idx = blockIdx.x * 256 + t;
    const int n = (idx < N_NODES) ? idx : (N_NODES - 1);
    float4 P = px4[n];
    float fn = f[n];
    {
        char* row = mybuf + lane * RS;
        *(uint4*)(row) = make_uint4(pk_bf16(P.x, P.y), pk_bf16(P.z, P.w),
                                    pk_bf16(fn, 0.f), 0u);
        *(uint4*)(row + 16) = make_uint4(0u, 0u, 0u, 0u);
        *(uint4*)(row + 32) = make_uint4(0u, 0u, 0u, 0u);
        *(uint4*)(row + 48) = make_uint4(0u, 0u, 0u, 0u);
    }
    __syncthreads();

    bf16x8 Wa1[4], Wa2[8], Wa3[8], Wa4[2];
#pragma unroll
    for (int mt = 0; mt < 4; mt++)
        Wa1[mt] = *(bf16x8*)(smem + DW1OFF + (mt * 16 + c) * 64 + q * 16);
#pragma unroll
    for (int mt = 0; mt < 4; mt++)
#pragma unroll
        for (int ks = 0; ks < 2; ks++) {
            Wa2[mt * 2 + ks] =
                *(bf16x8*)(smem + DW2OFF + (mt * 16 + c) * RS + ks * 64 + q * 16);
            Wa3[mt * 2 + ks] =
                *(bf16x8*)(smem + DW3OFF + (mt * 16 + c) * RS + ks * 64 + q * 16);
        }
#pragma unroll
    for (int ks = 0; ks < 2; ks++)
        Wa4[ks] = *(bf16x8*)(smem + DW4OFF + c * RS + ks * 64 + q * 16);
    float4 b1v[4], b2v[4], b3v[4], b4v;
#pragma unroll
    for (int mt = 0; mt < 4; mt++) {
        b1v[mt] = *(const float4*)(smem + DB1 + (mt * 16 + q * 4) * 4);
        b2v[mt] = *(const float4*)(smem + DB2 + (mt * 16 + q * 4) * 4);
        b3v[mt] = *(const float4*)(smem + DB3 + (mt * 16 + q * 4) * 4);
    }
    b4v = *(const float4*)(smem + DB4 + q * 16);

#pragma unroll
    for (int nt = 0; nt < 4; nt++) {
        char* rowb = mybuf + (nt * 16 + c) * RS;
        bf16x8 Eb = *(bf16x8*)(rowb + q * 16);
        f32x4 a1v[4];
#pragma unroll
        for (int mt = 0; mt < 4; mt++) {
            a1v[mt] = (f32x4){b1v[mt].x, b1v[mt].y, b1v[mt].z, b1v[mt].w};
            a1v[mt] = __builtin_amdgcn_mfma_f32_16x16x32_bf16(Wa1[mt], Eb, a1v[mt], 0, 0, 0);
        }
#pragma unroll
        for (int mt = 0; mt < 4; mt++)
            *(uint2*)(rowb + mt * 32 + q * 8) = make_uint2(
                pk_bf16(fmaxf(a1v[mt][0], 0.f), fmaxf(a1v[mt][1], 0.f)),
                pk_bf16(fmaxf(a1v[mt][2], 0.f), fmaxf(a1v[mt][3], 0.f)));
        bf16x8 H0 = *(bf16x8*)(rowb + q * 16);
        bf16x8 H1 = *(bf16x8*)(rowb + 64 + q * 16);
        f32x4 a2v[4];
#pragma unroll
        for (int mt = 0; mt < 4; mt++) {
            a2v[mt] = (f32x4){b2v[mt].x, b2v[mt].y, b2v[mt].z, b2v[mt].w};
            a2v[mt] = __builtin_amdgcn_mfma_f32_16x16x32_bf16(Wa2[mt * 2 + 0], H0, a2v[mt], 0, 0, 0);
            a2v[mt] = __builtin_amdgcn_mfma_f32_16x16x32_bf16(Wa2[mt * 2 + 1], H1, a2v[mt], 0, 0, 0);
        }
#pragma unroll
        for (int mt = 0; mt < 4; mt++)
            *(uint2*)(rowb + mt * 32 + q * 8) = make_uint2(
                pk_bf16(fmaxf(a2v[mt][0], 0.f), fmaxf(a2v[mt][1], 0.f)),
                pk_bf16(fmaxf(a2v[mt][2], 0.f), fmaxf(a2v[mt][3], 0.f)));
        bf16x8 G0 = *(bf16x8*)(rowb + q * 16);
        bf16x8 G1 = *(bf16x8*)(rowb + 64 + q * 16);
        f32x4 a3v[4];
#pragma unroll
        for (int mt = 0; mt < 4; mt++) {
            a3v[mt] = (f32x4){b3v[mt].x, b3v[mt].y, b3v[mt].z, b3v[mt].w};
            a3v[mt] = __builtin_amdgcn_mfma_f32_16x16x32_bf16(Wa3[mt * 2 + 0], G0, a3v[mt], 0, 0, 0);
            a3v[mt] = __builtin_amdgcn_mfma_f32_16x16x32_bf16(Wa3[mt * 2 + 1], G1, a3v[mt], 0, 0, 0);
        }
#pragma unroll
        for (int mt = 0; mt < 4; mt++)
            *(uint2*)(rowb + mt * 32 + q * 8) = make_uint2(
                pk_bf16(fmaxf(a3v[mt][0], 0.f), fmaxf(a3v[mt][1], 0.f)),
                pk_bf16(fmaxf(a3v[mt][2], 0.f), fmaxf(a3v[mt][3], 0.f)));
        bf16x8 F0 = *(bf16x8*)(rowb + q * 16);
        bf16x8 F1 = *(bf16x8*)(rowb + 64 + q * 16);
        f32x4 a4 = (f32x4){b4v.x, b4v.y, b4v.z, b4v.w};
        a4 = __builtin_amdgcn_mfma_f32_16x16x32_bf16(Wa4[0], F0, a4, 0, 0, 0);
        a4 = __builtin_amdgcn_mfma_f32_16x16x32_bf16(Wa4[1], F1, a4, 0, 0, 0);
        if (q == 0) *(float*)(rowb + 128) = a4[0];
    }

    float o = *(float*)(mybuf + lane * RS + 128);
    if (idx < N_NODES) out[n] = yp[n] + o;
}

extern "C" void kernel_launch(void* const* d_in, const int* in_sizes, int n_in,
                              void* d_out, int out_size, void* d_ws, size_t ws_size,
                              hipStream_t stream) {
    const float* X    = (const float*)d_in[0];
    const float* yp   = (const float*)d_in[1];
    const int*   edge = (const int*)d_in[2];
    const float *ew1 = (const float*)d_in[3],  *eb1 = (const float*)d_in[4];
    const float *ew2 = (const float*)d_in[5],  *eb2 = (const float*)d_in[6];
    const float *ew3 = (const float*)d_in[7],  *eb3 = (const float*)d_in[8];
    const float *nw1 = (const float*)d_in[9],  *nb1 = (const float*)d_in[10];
    const float *nw2 = (const float*)d_in[11], *nb2 = (const float*)d_in[12];
    const float *nw3 = (const float*)d_in[13], *nb3 = (const float*)d_in[14];
    const float *dw1 = (const float*)d_in[15], *db1 = (const float*)d_in[16];
    const float *dw2 = (const float*)d_in[17], *db2 = (const float*)d_in[18];
    const float *dw3 = (const float*)d_in[19], *db3 = (const float*)d_in[20];
    const float *dw4 = (const float*)d_in[21], *db4 = (const float*)d_in[22];
    float* out = (float*)d_out;

    char* p = (char*)d_ws;
    auto carve = [&](size_t bytes) {
        char* r = p;
        p += (bytes + 255) & ~(size_t)255;
        return r;
    };
    int2*   sd      = (int2*)  carve(sizeof(int2)   * N_EDGES);
    float4* dnrm    = (float4*)carve(sizeof(float4) * N_EDGES);
    float4* ea      = (float4*)carve(sizeof(float4) * N_EDGES);
    int2*   staging = (int2*)  carve(sizeof(int2)   * SCAN_NB * MAXB);
    float4* px4     = (float4*)carve(sizeof(float4) * N_NODES);
    float*  f       = (float*) carve(sizeof(float)  * N_NODES);
    int*    rowptr  = (int*)   carve(sizeof(int)    * (N_NODES + 1));
    int*    btail   = (int*)   carve(sizeof(int)    * 256);
    int*    bbase   = (int*)   carve(sizeof(int)    * 256);
    char*   eimg    = (char*)  carve(EIMG_B);
    char*   nimg    = (char*)  carve(EIMG_B);
    char*   dimg    = (char*)  carve(DIMG_B);

    const int nb_n = SCAN_NB;                 // 196
    const int nb_e = (N_EDGES + 255) / 256;   // 3125, exact
    const int nb_b = (N_EDGES + 2047) / 2048; // 391

    hipMemsetAsync(btail, 0, sizeof(int) * 256, stream);
    k_node_init<<<nb_n, 256, 0, stream>>>(X, yp, px4, f);
    k_prep<<<3, 256, 0, stream>>>(ew1, ew2, ew3, eb1, eb2, eb3,
                                  nw1, nw2, nw3, nb1, nb2, nb3,
                                  dw1, dw2, dw3, dw4, db1, db2, db3, db4,
                                  eimg, nimg, dimg);
    k_bucket<<<nb_b, 256, 0, stream>>>(edge, btail, staging);
    k_bscan<<<1, 256, 0, stream>>>(btail, bbase);
    k_bsort<<<nb_n, 256, 0, stream>>>(staging, btail, bbase, sd, rowptr);
    k_edge_init<<<nb_e, 256, 0, stream>>>(sd, px4, yp, dnrm, ea);

    for (int it = 0; it < 3; ++it) {
        k_edge_mlp<<<nb_e, 256, 0, stream>>>(sd, dnrm, ea, f, eimg);
        k_node_mlp<<<nb_n, 256, 0, stream>>>(px4, f, ea, rowptr, nimg);
    }
    k_decoder<<<nb_n, 256, 0, stream>>>(px4, f, yp, dimg, out);
}

// Round 16
// 270.025 us; speedup vs baseline: 1.0940x; 1.0299x over previous
//
#include <hip/hip_runtime.h>
#include <math.h>

#define N_NODES 50000
#define N_EDGES 800000
#define EPS 1e-12f
#define SCAN_NB 196   // ceil(50000/256) node blocks; also bucket count (dst>>8)
#define MAXB 6144     // per-bucket capacity (mean 4082)

typedef __attribute__((ext_vector_type(8))) short bf16x8;
typedef __attribute__((ext_vector_type(4))) float f32x4;

__device__ inline unsigned pk_bf16(float a, float b) {
    unsigned ua = __float_as_uint(a), ub = __float_as_uint(b);
    ua = (ua + 0x7FFFu + ((ua >> 16) & 1u)) >> 16;
    ub = (ub + 0x7FFFu + ((ub >> 16) & 1u)) >> 16;
    return ua | (ub << 16);
}

// image layouts (weights bf16 + biases fp32)
#define W1OFF 0
#define W2OFF 4096
#define W3OFF 13312
#define RS 144
#define EB1 15616
#define EB2 15872
#define EB3 16128
#define EIMG_B 16192     // also NIMG_B
#define DW1OFF 0
#define DW2OFF 4096
#define DW3OFF 13312
#define DW4OFF 22528
#define DB1 24832
#define DB2 25088
#define DB3 25344
#define DB4 25600
#define DIMG_B 25664

// ---------------- K0: per-node precompute ----------------
__global__ void k_node_init(const float* __restrict__ X, const float* __restrict__ yp,
                            float4* __restrict__ px4, float* __restrict__ f) {
    int n = blockIdx.x * blockDim.x + threadIdx.x;
    if (n < N_NODES) {
        px4[n] = make_float4(X[n * 6 + 0], X[n * 6 + 1], X[n * 6 + 2], X[n * 6 + 4]);
        f[n] = yp[n];
    }
}

// ---------------- KP: one-shot bf16 weight-image + fp32 bias prep -----------
__global__ __launch_bounds__(256) void k_prep(
    const float* __restrict__ ew1, const float* __restrict__ ew2,
    const float* __restrict__ ew3, const float* __restrict__ eb1,
    const float* __restrict__ eb2, const float* __restrict__ eb3,
    const float* __restrict__ nw1, const float* __restrict__ nw2,
    const float* __restrict__ nw3, const float* __restrict__ nb1,
    const float* __restrict__ nb2, const float* __restrict__ nb3,
    const float* __restrict__ dw1, const float* __restrict__ dw2,
    const float* __restrict__ dw3, const float* __restrict__ dw4,
    const float* __restrict__ db1, const float* __restrict__ db2,
    const float* __restrict__ db3, const float* __restrict__ db4,
    char* __restrict__ eimg, char* __restrict__ nimg, char* __restrict__ dimg) {
    const int t = threadIdx.x;
    const int n = t & 63, kg = t >> 6;
    const int n3 = t & 15, kg3 = t >> 4;
    if (blockIdx.x == 0) {
        unsigned pk[4];
#pragma unroll
        for (int i = 0; i < 4; i++) {
            int k0 = kg * 8 + i * 2;
            float v0 = (k0 < 9) ? ew1[k0 * 64 + n] : 0.f;
            float v1 = (k0 + 1 < 9) ? ew1[(k0 + 1) * 64 + n] : 0.f;
            pk[i] = pk_bf16(v0, v1);
        }
        *(uint4*)(eimg + W1OFF + n * 64 + kg * 16) = make_uint4(pk[0], pk[1], pk[2], pk[3]);
        unsigned pk2[8];
#pragma unroll
        for (int i = 0; i < 8; i++) {
            int k0 = kg * 16 + i * 2;
            pk2[i] = pk_bf16(ew2[k0 * 64 + n], ew2[(k0 + 1) * 64 + n]);
        }
        *(uint4*)(eimg + W2OFF + n * RS + kg * 32) = make_uint4(pk2[0], pk2[1], pk2[2], pk2[3]);
        *(uint4*)(eimg + W2OFF + n * RS + kg * 32 + 16) = make_uint4(pk2[4], pk2[5], pk2[6], pk2[7]);
        unsigned pk3[2];
#pragma unroll
        for (int i = 0; i < 2; i++) {
            int k0 = kg3 * 4 + i * 2;
            float v0 = (n3 < 3) ? ew3[k0 * 3 + n3] : 0.f;
            float v1 = (n3 < 3) ? ew3[(k0 + 1) * 3 + n3] : 0.f;
            pk3[i] = pk_bf16(v0, v1);
        }
        *(uint2*)(eimg + W3OFF + n3 * RS + kg3 * 8) = make_uint2(pk3[0], pk3[1]);
        if (t < 64) {
            ((float*)(eimg + EB1))[t] = eb1[t];
            ((float*)(eimg + EB2))[t] = eb2[t];
        }
        if (t < 16) ((float*)(eimg + EB3))[t] = (t < 3) ? eb3[t] : 0.f;
    } else if (blockIdx.x == 1) {
        unsigned pk[4];
#pragma unroll
        for (int i = 0; i < 4; i++) {
            int k0 = kg * 8 + i * 2;
            float v0 = (k0 < 5) ? nw1[k0 * 64 + n] : 0.f;
            float v1 = (k0 + 1 < 5) ? nw1[(k0 + 1) * 64 + n] : 0.f;
            pk[i] = pk_bf16(v0, v1);
        }
        *(uint4*)(nimg + W1OFF + n * 64 + kg * 16) = make_uint4(pk[0], pk[1], pk[2], pk[3]);
        unsigned pk2[8];
#pragma unroll
        for (int i = 0; i < 8; i++) {
            int k0 = kg * 16 + i * 2;
            pk2[i] = pk_bf16(nw2[k0 * 64 + n], nw2[(k0 + 1) * 64 + n]);
        }
        *(uint4*)(nimg + W2OFF + n * RS + kg * 32) = make_uint4(pk2[0], pk2[1], pk2[2], pk2[3]);
        *(uint4*)(nimg + W2OFF + n * RS + kg * 32 + 16) = make_uint4(pk2[4], pk2[5], pk2[6], pk2[7]);
        unsigned pk3[2];
#pragma unroll
        for (int i = 0; i < 2; i++) {
            int k0 = kg3 * 4 + i * 2;
            float v0 = (n3 == 0) ? nw3[k0] : 0.f;
            float v1 = (n3 == 0) ? nw3[k0 + 1] : 0.f;
            pk3[i] = pk_bf16(v0, v1);
        }
        *(uint2*)(nimg + W3OFF + n3 * RS + kg3 * 8) = make_uint2(pk3[0], pk3[1]);
        if (t < 64) {
            ((float*)(nimg + EB1))[t] = nb1[t];
            ((float*)(nimg + EB2))[t] = nb2[t];
        }
        if (t < 16) ((float*)(nimg + EB3))[t] = (t == 0) ? nb3[0] : 0.f;
    } else {
        unsigned pk[4];
#pragma unroll
        for (int i = 0; i < 4; i++) {
            int k0 = kg * 8 + i * 2;
            float v0 = (k0 < 5) ? dw1[k0 * 64 + n] : 0.f;
            float v1 = (k0 + 1 < 5) ? dw1[(k0 + 1) * 64 + n] : 0.f;
            pk[i] = pk_bf16(v0, v1);
        }
        *(uint4*)(dimg + DW1OFF + n * 64 + kg * 16) = make_uint4(pk[0], pk[1], pk[2], pk[3]);
        unsigned pk2[8], pk3b[8];
#pragma unroll
        for (int i = 0; i < 8; i++) {
            int k0 = kg * 16 + i * 2;
            pk2[i] = pk_bf16(dw2[k0 * 64 + n], dw2[(k0 + 1) * 64 + n]);
            pk3b[i] = pk_bf16(dw3[k0 * 64 + n], dw3[(k0 + 1) * 64 + n]);
        }
        *(uint4*)(dimg + DW2OFF + n * RS + kg * 32) = make_uint4(pk2[0], pk2[1], pk2[2], pk2[3]);
        *(uint4*)(dimg + DW2OFF + n * RS + kg * 32 + 16) = make_uint4(pk2[4], pk2[5], pk2[6], pk2[7]);
        *(uint4*)(dimg + DW3OFF + n * RS + kg * 32) = make_uint4(pk3b[0], pk3b[1], pk3b[2], pk3b[3]);
        *(uint4*)(dimg + DW3OFF + n * RS + kg * 32 + 16) = make_uint4(pk3b[4], pk3b[5], pk3b[6], pk3b[7]);
        unsigned pk4[2];
#pragma unroll
        for (int i = 0; i < 2; i++) {
            int k0 = kg3 * 4 + i * 2;
            float v0 = (n3 == 0) ? dw4[k0] : 0.f;
            float v1 = (n3 == 0) ? dw4[k0 + 1] : 0.f;
            pk4[i] = pk_bf16(v0, v1);
        }
        *(uint2*)(dimg + DW4OFF + n3 * RS + kg3 * 8) = make_uint2(pk4[0], pk4[1]);
        if (t < 64) {
            ((float*)(dimg + DB1))[t] = db1[t];
            ((float*)(dimg + DB2))[t] = db2[t];
            ((float*)(dimg + DB3))[t] = db3[t];
        }
        if (t < 16) ((float*)(dimg + DB4))[t] = (t == 0) ? db4[0] : 0.f;
    }
}

// ---------------- S1: coarse bucket (dst>>8) ----------------
__global__ __launch_bounds__(256) void k_bucket(const int* __restrict__ edge,
                                                int* __restrict__ btail,
                                                int2* __restrict__ staging) {
    __shared__ int hist[256], loff[256], gbase[256], fill[256];
    __shared__ int2 ebL[2048];
    __shared__ unsigned short bktL[2048];
    const int t = threadIdx.x;
    const int base = blockIdx.x * 2048;
    const int cnt = min(2048, N_EDGES - base);
    hist[t] = 0; fill[t] = 0;
    __syncthreads();

    int2 my[8]; int mb[8];
#pragma unroll
    for (int j = 0; j < 8; j++) {
        int i = base + t + j * 256;
        if (i < N_EDGES) {
            int s = edge[i], d = edge[N_EDGES + i];
            my[j] = make_int2(s, d);
            mb[j] = d >> 8;
            atomicAdd(&hist[mb[j]], 1);
        } else mb[j] = -1;
    }
    __syncthreads();
    int v = hist[t];
    loff[t] = v;
    __syncthreads();
    for (int off = 1; off < 256; off <<= 1) {
        int x = (t >= off) ? loff[t - off] : 0;
        __syncthreads();
        loff[t] += x;
        __syncthreads();
    }
    int ex = loff[t] - v;
    __syncthreads();
    loff[t] = ex;
    if (v > 0) gbase[t] = atomicAdd(&btail[t], v);
    __syncthreads();
#pragma unroll
    for (int j = 0; j < 8; j++) {
        if (mb[j] >= 0) {
            int lp = loff[mb[j]] + atomicAdd(&fill[mb[j]], 1);
            ebL[lp] = my[j];
            bktL[lp] = (unsigned short)mb[j];
        }
    }
    __syncthreads();
    for (int i = t; i < cnt; i += 256) {
        int b = bktL[i];
        int gp = gbase[b] + (i - loff[b]);
        if (gp < MAXB) staging[b * MAXB + gp] = ebL[i];
    }
}

// ---------------- S2: exclusive scan of bucket sizes ----------------
__global__ void k_bscan(const int* __restrict__ btail, int* __restrict__ bbase) {
    __shared__ int s[256];
    int t = threadIdx.x;
    int v = (t < SCAN_NB) ? btail[t] : 0;
    s[t] = v;
    __syncthreads();
    for (int off = 1; off < 256; off <<= 1) {
        int x = (t >= off) ? s[t - off] : 0;
        __syncthreads();
        s[t] += x;
        __syncthreads();
    }
    if (t < SCAN_NB) bbase[t] = s[t] - v;
}

// ---------------- S3: per-bucket fine sort -> sd + rowptr ----------------
__global__ __launch_bounds__(256) void k_bsort(const int2* __restrict__ staging,
                                               const int* __restrict__ btail,
                                               const int* __restrict__ bbase,
                                               int2* __restrict__ sd,
                                               int* __restrict__ rowptr) {
    __shared__ int hist[256], excl[256], fill[256], sbuf[256];
    __shared__ int2 ebL[MAXB];
    const int b = blockIdx.x, t = threadIdx.x;
    const int size = min(btail[b], MAXB);
    const int gb = bbase[b];
    for (int i = t; i < size; i += 256) ebL[i] = staging[b * MAXB + i];
    hist[t] = 0; fill[t] = 0;
    __syncthreads();
    for (int i = t; i < size; i += 256) atomicAdd(&hist[ebL[i].y & 255], 1);
    __syncthreads();
    int v = hist[t];
    sbuf[t] = v;
    __syncthreads();
    for (int off = 1; off < 256; off <<= 1) {
        int x = (t >= off) ? sbuf[t - off] : 0;
        __syncthreads();
        sbuf[t] += x;
        __syncthreads();
    }
    int ex = sbuf[t] - v;
    excl[t] = ex;
    int n = (b << 8) + t;
    if (n < N_NODES) rowptr[n] = gb + ex;
    if (b == SCAN_NB - 1 && t == 0) rowptr[N_NODES] = N_EDGES;
    __syncthreads();
    for (int i = t; i < size; i += 256) {
        int2 v2 = ebL[i];
        int ld = v2.y & 255;
        int pos = excl[ld] + atomicAdd(&fill[ld], 1);
        sd[gb + pos] = v2;
    }
}

// ---------------- K1: per-edge precompute (sorted order) --------
__global__ void k_edge_init(const int2* __restrict__ sd,
                            const float4* __restrict__ px4,
                            const float* __restrict__ yp,
                            float4* __restrict__ dnrm, float4* __restrict__ ea) {
    int e = blockIdx.x * blockDim.x + threadIdx.x;
    if (e < N_EDGES) {
        int2 SD = sd[e];
        float4 ps = px4[SD.x], pd = px4[SD.y];
        float dx = pd.x - ps.x, dy = pd.y - ps.y, dz = pd.z - ps.z;
        float nrm = sqrtf(dx * dx + dy * dy + dz * dz + EPS);
        dnrm[e] = make_float4(dx, dy, dz, nrm);
        float fr = yp[SD.y] - yp[SD.x];
        ea[e] = make_float4(fr * dx, fr * dy, fr * dz, 0.f);
    }
}

// ---------------- K2: edge MLP, wave-sized blocks (64 thr = 1 wave) ---------
// No barrier coupling: __syncthreads in a single-wave block is just s_waitcnt.
// Weights/biases hoisted from L2-resident global image.
__global__ __launch_bounds__(64, 3) void k_edge_mlp(
    const int2* __restrict__ sd, const float4* __restrict__ dnrm,
    float4* __restrict__ ea, const float* __restrict__ f,
    const char* __restrict__ eimg) {
    __shared__ __align__(16) char mybuf[64 * RS];  // 9.2 KB, one wave
    const int lane = threadIdx.x;
    const int c = lane & 15, q = lane >> 4;

    const int e = blockIdx.x * 64 + lane;
    int2 SD = sd[e];
    float4 DN = dnrm[e];
    float4 EA = ea[e];
    float fs = f[SD.x], fd = f[SD.y];

    // hoisted weight fragments + biases (L2-resident, wave-uniform addresses)
    bf16x8 Wa1[4], Wa2[8], Wa3[2];
#pragma unroll
    for (int mt = 0; mt < 4; mt++)
        Wa1[mt] = *(const bf16x8*)(eimg + W1OFF + (mt * 16 + c) * 64 + q * 16);
#pragma unroll
    for (int mt = 0; mt < 4; mt++)
#pragma unroll
        for (int ks = 0; ks < 2; ks++)
            Wa2[mt * 2 + ks] =
                *(const bf16x8*)(eimg + W2OFF + (mt * 16 + c) * RS + ks * 64 + q * 16);
#pragma unroll
    for (int ks = 0; ks < 2; ks++)
        Wa3[ks] = *(const bf16x8*)(eimg + W3OFF + c * RS + ks * 64 + q * 16);
    float4 b1v[4], b2v[4], b3v;
#pragma unroll
    for (int mt = 0; mt < 4; mt++) {
        b1v[mt] = *(const float4*)(eimg + EB1 + (mt * 16 + q * 4) * 4);
        b2v[mt] = *(const float4*)(eimg + EB2 + (mt * 16 + q * 4) * 4);
    }
    b3v = *(const float4*)(eimg + EB3 + q * 16);

    {
        char* row = mybuf + lane * RS;
        *(uint4*)(row) = make_uint4(pk_bf16(DN.x, DN.y), pk_bf16(DN.z, DN.w),
                                    pk_bf16(EA.x, EA.y), pk_bf16(EA.z, fs));
        *(uint4*)(row + 16) = make_uint4(pk_bf16(fd, 0.f), 0u, 0u, 0u);
        *(uint4*)(row + 32) = make_uint4(0u, 0u, 0u, 0u);
        *(uint4*)(row + 48) = make_uint4(0u, 0u, 0u, 0u);
    }
    __syncthreads();  // single-wave: compiles to s_waitcnt, no s_barrier

#pragma unroll
    for (int nt = 0; nt < 4; nt++) {
        char* rowb = mybuf + (nt * 16 + c) * RS;
        // layer 1
        bf16x8 Eb = *(bf16x8*)(rowb + q * 16);
        f32x4 a1[4];
#pragma unroll
        for (int mt = 0; mt < 4; mt++) {
            a1[mt] = (f32x4){b1v[mt].x, b1v[mt].y, b1v[mt].z, b1v[mt].w};
            a1[mt] = __builtin_amdgcn_mfma_f32_16x16x32_bf16(Wa1[mt], Eb, a1[mt], 0, 0, 0);
        }
#pragma unroll
        for (int mt = 0; mt < 4; mt++)
            *(uint2*)(rowb + mt * 32 + q * 8) = make_uint2(
                pk_bf16(fmaxf(a1[mt][0], 0.f), fmaxf(a1[mt][1], 0.f)),
                pk_bf16(fmaxf(a1[mt][2], 0.f), fmaxf(a1[mt][3], 0.f)));
        // layer 2
        bf16x8 H0 = *(bf16x8*)(rowb + q * 16);
        bf16x8 H1 = *(bf16x8*)(rowb + 64 + q * 16);
        f32x4 a2[4];
#pragma unroll
        for (int mt = 0; mt < 4; mt++) {
            a2[mt] = (f32x4){b2v[mt].x, b2v[mt].y, b2v[mt].z, b2v[mt].w};
            a2[mt] = __builtin_amdgcn_mfma_f32_16x16x32_bf16(Wa2[mt * 2 + 0], H0, a2[mt], 0, 0, 0);
            a2[mt] = __builtin_amdgcn_mfma_f32_16x16x32_bf16(Wa2[mt * 2 + 1], H1, a2[mt], 0, 0, 0);
        }
#pragma unroll
        for (int mt = 0; mt < 4; mt++)
            *(uint2*)(rowb + mt * 32 + q * 8) = make_uint2(
                pk_bf16(fmaxf(a2[mt][0], 0.f), fmaxf(a2[mt][1], 0.f)),
                pk_bf16(fmaxf(a2[mt][2], 0.f), fmaxf(a2[mt][3], 0.f)));
        // layer 3 (64 -> 3)
        bf16x8 G0 = *(bf16x8*)(rowb + q * 16);
        bf16x8 G1 = *(bf16x8*)(rowb + 64 + q * 16);
        f32x4 a3 = (f32x4){b3v.x, b3v.y, b3v.z, b3v.w};
        a3 = __builtin_amdgcn_mfma_f32_16x16x32_bf16(Wa3[0], G0, a3, 0, 0, 0);
        a3 = __builtin_amdgcn_mfma_f32_16x16x32_bf16(Wa3[1], G1, a3, 0, 0, 0);
        if (q == 0)
            *(float4*)(rowb + 128) = make_float4(a3[0], a3[1], a3[2], a3[3]);
    }
    __syncthreads();

    float4 o = *(float4*)(mybuf + lane * RS + 128);
    ea[e] = make_float4(EA.x + o.x, EA.y + o.y, EA.z + o.z, 0.f);
}

// ---------------- K3: segment-mean + node MLP (R12 version) -----------------
__global__ __launch_bounds__(256, 2) void k_node_mlp(
    const float4* __restrict__ px4, float* __restrict__ f,
    const float4* __restrict__ ea, const int* __restrict__ rowptr,
    const char* __restrict__ nimg) {
    __shared__ __align__(16) char smem[EIMG_B + 4 * 64 * RS];
    const int t = threadIdx.x;
    const int lane = t & 63, wave = t >> 6;
    const int c = lane & 15, q = lane >> 4;

    for (int i = t; i < EIMG_B / 16; i += 256)
        ((uint4*)smem)[i] = ((const uint4*)nimg)[i];

    char* mybuf = smem + EIMG_B + wave * (64 * RS);
    const int idx = blockIdx.x * 256 + t;
    const int n = (idx < N_NODES) ? idx : (N_NODES - 1);

    int b0 = rowptr[n], b1 = rowptr[n + 1];
    float a0 = 0.f, a1s = 0.f, a2s = 0.f;
    for (int p = b0; p < b1; p++) {
        float4 v = ea[p];
        a0 += v.x; a1s += v.y; a2s += v.z;
    }
    float inv = 1.0f / fmaxf((float)(b1 - b0), 1.0f);
    float4 P = px4[n];
    float fn = f[n];
    {
        char* row = mybuf + lane * RS;
        *(uint4*)(row) = make_uint4(pk_bf16(P.w, fn), pk_bf16(a0 * inv, a1s * inv),
                                    pk_bf16(a2s * inv, 0.f), 0u);
        *(uint4*)(row + 16) = make_uint4(0u, 0u, 0u, 0u);
        *(uint4*)(row + 32) = make_uint4(0u, 0u, 0u, 0u);
        *(uint4*)(row + 48) = make_uint4(0u, 0u, 0u, 0u);
    }
    __syncthreads();

    bf16x8 Wa1[4], Wa2[8], Wa3[2];
#pragma unroll
    for (int mt = 0; mt < 4; mt++)
        Wa1[mt] = *(bf16x8*)(smem + W1OFF + (mt * 16 + c) * 64 + q * 16);
#pragma unroll
    for (int mt = 0; mt < 4; mt++)
#pragma unroll
        for (int ks = 0; ks < 2; ks++)
            Wa2[mt * 2 + ks] =
                *(bf16x8*)(smem + W2OFF + (mt * 16 + c) * RS + ks * 64 + q * 16);
#pragma unroll
    for (int ks = 0; ks < 2; ks++)
        Wa3[ks] = *(bf16x8*)(smem + W3OFF + c * RS + ks * 64 + q * 16);
    float4 b1v[4], b2v[4], b3v;
#pragma unroll
    for (int mt = 0; mt < 4; mt++) {
        b1v[mt] = *(const float4*)(smem + EB1 + (mt * 16 + q * 4) * 4);
        b2v[mt] = *(const float4*)(smem + EB2 + (mt * 16 + q * 4) * 4);
    }
    b3v = *(const float4*)(smem + EB3 + q * 16);

#pragma unroll
    for (int nt = 0; nt < 4; nt++) {
        char* rowb = mybuf + (nt * 16 + c) * RS;
        bf16x8 Eb = *(bf16x8*)(rowb + q * 16);
        f32x4 a1v[4];
#pragma unroll
        for (int mt = 0; mt < 4; mt++) {
            a1v[mt] = (f32x4){b1v[mt].x, b1v[mt].y, b1v[mt].z, b1v[mt].w};
            a1v[mt] = __builtin_amdgcn_mfma_f32_16x16x32_bf16(Wa1[mt], Eb, a1v[mt], 0, 0, 0);
        }
#pragma unroll
        for (int mt = 0; mt < 4; mt++)
            *(uint2*)(rowb + mt * 32 + q * 8) = make_uint2(
                pk_bf16(fmaxf(a1v[mt][0], 0.f), fmaxf(a1v[mt][1], 0.f)),
                pk_bf16(fmaxf(a1v[mt][2], 0.f), fmaxf(a1v[mt][3], 0.f)));
        bf16x8 H0 = *(bf16x8*)(rowb + q * 16);
        bf16x8 H1 = *(bf16x8*)(rowb + 64 + q * 16);
        f32x4 a2v[4];
#pragma unroll
        for (int mt = 0; mt < 4; mt++) {
            a2v[mt] = (f32x4){b2v[mt].x, b2v[mt].y, b2v[mt].z, b2v[mt].w};
            a2v[mt] = __builtin_amdgcn_mfma_f32_16x16x32_bf16(Wa2[mt * 2 + 0], H0, a2v[mt], 0, 0, 0);
            a2v[mt] = __builtin_amdgcn_mfma_f32_16x16x32_bf16(Wa2[mt * 2 + 1], H1, a2v[mt], 0, 0, 0);
        }
#pragma unroll
        for (int mt = 0; mt < 4; mt++)
            *(uint2*)(rowb + mt * 32 + q * 8) = make_uint2(
                pk_bf16(fmaxf(a2v[mt][0], 0.f), fmaxf(a2v[mt][1], 0.f)),
                pk_bf16(fmaxf(a2v[mt][2], 0.f), fmaxf(a2v[mt][3], 0.f)));
        bf16x8 G0 = *(bf16x8*)(rowb + q * 16);
        bf16x8 G1 = *(bf16x8*)(rowb + 64 + q * 16);
        f32x4 a3 = (f32x4){b3v.x, b3v.y, b3v.z, b3v.w};
        a3 = __builtin_amdgcn_mfma_f32_16x16x32_bf16(Wa3[0], G0, a3, 0, 0, 0);
        a3 = __builtin_amdgcn_mfma_f32_16x16x32_bf16(Wa3[1], G1, a3, 0, 0, 0);
        if (q == 0) *(float*)(rowb + 128) = a3[0];
    }

    float o = *(float*)(mybuf + lane * RS + 128);
    if (idx < N_NODES) f[n] = fn + o;
}

// ---------------- K4: decoder (R12 version) ----------
__global__ __launch_bounds__(256, 2) void k_decoder(
    const float4* __restrict__ px4, const float* __restrict__ f,
    const float* __restrict__ yp, const char* __restrict__ dimg,
    float* __restrict__ out) {
    __shared__ __align__(16) char smem[DIMG_B + 4 * 64 * RS];
    const int t = threadIdx.x;
    const int lane = t & 63, wave = t >> 6;
    const int c = lane & 15, q = lane >> 4;

    for (int i = t; i < DIMG_B / 16; i += 256)
        ((uint4*)smem)[i] = ((const uint4*)dimg)[i];

    char* mybuf = smem + DIMG_B + wave * (64 * RS);
    const int idx = blockIdx.x * 256 + t;
    const int n = (idx < N_NODES) ? idx : (N_NODES - 1);
    float4 P = px4[n];
    float fn = f[n];
    {
        char* row = mybuf + lane * RS;
        *(uint4*)(row) = make_uint4(pk_bf16(P.x, P.y), pk_bf16(P.z, P.w),
                                    pk_bf16(fn, 0.f), 0u);
        *(uint4*)(row + 16) = make_uint4(0u, 0u, 0u, 0u);
        *(uint4*)(row + 32) = make_uint4(0u, 0u, 0u, 0u);
        *(uint4*)(row + 48) = make_uint4(0u, 0u, 0u, 0u);
    }
    __syncthreads();

    bf16x8 Wa1[4], Wa2[8], Wa3[8], Wa4[2];
#pragma unroll
    for (int mt = 0; mt < 4; mt++)
        Wa1[mt] = *(bf16x8*)(smem + DW1OFF + (mt * 16 + c) * 64 + q * 16);
#pragma unroll
    for (int mt = 0; mt < 4; mt++)
#pragma unroll
        for (int ks = 0; ks < 2; ks++) {
            Wa2[mt * 2 + ks] =
                *(bf16x8*)(smem + DW2OFF + (mt * 16 + c) * RS + ks * 64 + q * 16);
            Wa3[mt * 2 + ks] =
                *(bf16x8*)(smem + DW3OFF + (mt * 16 + c) * RS + ks * 64 + q * 16);
        }
#pragma unroll
    for (int ks = 0; ks < 2; ks++)
        Wa4[ks] = *(bf16x8*)(smem + DW4OFF + c * RS + ks * 64 + q * 16);
    float4 b1v[4], b2v[4], b3v[4], b4v;
#pragma unroll
    for (int mt = 0; mt < 4; mt++) {
        b1v[mt] = *(const float4*)(smem + DB1 + (mt * 16 + q * 4) * 4);
        b2v[mt] = *(const float4*)(smem + DB2 + (mt * 16 + q * 4) * 4);
        b3v[mt] = *(const float4*)(smem + DB3 + (mt * 16 + q * 4) * 4);
    }
    b4v = *(const float4*)(smem + DB4 + q * 16);

#pragma unroll
    for (int nt = 0; nt < 4; nt++) {
        char* rowb = mybuf + (nt * 16 + c) * RS;
        bf16x8 Eb = *(bf16x8*)(rowb + q * 16);
        f32x4 a1v[4];
#pragma unroll
        for (int mt = 0; mt < 4; mt++) {
            a1v[mt] = (f32x4){b1v[mt].x, b1v[mt].y, b1v[mt].z, b1v[mt].w};
            a1v[mt] = __builtin_amdgcn_mfma_f32_16x16x32_bf16(Wa1[mt], Eb, a1v[mt], 0, 0, 0);
        }
#pragma unroll
        for (int mt = 0; mt < 4; mt++)
            *(uint2*)(rowb + mt * 32 + q * 8) = make_uint2(
                pk_bf16(fmaxf(a1v[mt][0], 0.f), fmaxf(a1v[mt][1], 0.f)),
                pk_bf16(fmaxf(a1v[mt][2], 0.f), fmaxf(a1v[mt][3], 0.f)));
        bf16x8 H0 = *(bf16x8*)(rowb + q * 16);
        bf16x8 H1 = *(bf16x8*)(rowb + 64 + q * 16);
        f32x4 a2v[4];
#pragma unroll
        for (int mt = 0; mt < 4; mt++) {
            a2v[mt] = (f32x4){b2v[mt].x, b2v[mt].y, b2v[mt].z, b2v[mt].w};
            a2v[mt] = __builtin_amdgcn_mfma_f32_16x16x32_bf16(Wa2[mt * 2 + 0], H0, a2v[mt], 0, 0, 0);
            a2v[mt] = __builtin_amdgcn_mfma_f32_16x16x32_bf16(Wa2[mt * 2 + 1], H1, a2v[mt], 0, 0, 0);
        }
#pragma unroll
        for (int mt = 0; mt < 4; mt++)
            *(uint2*)(rowb + mt * 32 + q * 8) = make_uint2(
                pk_bf16(fmaxf(a2v[mt][0], 0.f), fmaxf(a2v[mt][1], 0.f)),
                pk_bf16(fmaxf(a2v[mt][2], 0.f), fmaxf(a2v[mt][3], 0.f)));
        bf16x8 G0 = *(bf16x8*)(rowb + q * 16);
        bf16x8 G1 = *(bf16x8*)(rowb + 64 + q * 16);
        f32x4 a3v[4];
#pragma unroll
        for (int mt = 0; mt < 4; mt++) {
            a3v[mt] = (f32x4){b3v[mt].x, b3v[mt].y, b3v[mt].z, b3v[mt].w};
            a3v[mt] = __builtin_amdgcn_mfma_f32_16x16x32_bf16(Wa3[mt * 2 + 0], G0, a3v[mt], 0, 0, 0);
            a3v[mt] = __builtin_amdgcn_mfma_f32_16x16x32_bf16(Wa3[mt * 2 + 1], G1, a3v[mt], 0, 0, 0);
        }
#pragma unroll
        for (int mt = 0; mt < 4; mt++)
            *(uint2*)(rowb + mt * 32 + q * 8) = make_uint2(
                pk_bf16(fmaxf(a3v[mt][0], 0.f), fmaxf(a3v[mt][1], 0.f)),
                pk_bf16(fmaxf(a3v[mt][2], 0.f), fmaxf(a3v[mt][3], 0.f)));
        bf16x8 F0 = *(bf16x8*)(rowb + q * 16);
        bf16x8 F1 = *(bf16x8*)(rowb + 64 + q * 16);
        f32x4 a4 = (f32x4){b4v.x, b4v.y, b4v.z, b4v.w};
        a4 = __builtin_amdgcn_mfma_f32_16x16x32_bf16(Wa4[0], F0, a4, 0, 0, 0);
        a4 = __builtin_amdgcn_mfma_f32_16x16x32_bf16(Wa4[1], F1, a4, 0, 0, 0);
        if (q == 0) *(float*)(rowb + 128) = a4[0];
    }

    float o = *(float*)(mybuf + lane * RS + 128);
    if (idx < N_NODES) out[n] = yp[n] + o;
}

extern "C" void kernel_launch(void* const* d_in, const int* in_sizes, int n_in,
                              void* d_out, int out_size, void* d_ws, size_t ws_size,
                              hipStream_t stream) {
    const float* X    = (const float*)d_in[0];
    const float* yp   = (const float*)d_in[1];
    const int*   edge = (const int*)d_in[2];
    const float *ew1 = (const float*)d_in[3],  *eb1 = (const float*)d_in[4];
    const float *ew2 = (const float*)d_in[5],  *eb2 = (const float*)d_in[6];
    const float *ew3 = (const float*)d_in[7],  *eb3 = (const float*)d_in[8];
    const float *nw1 = (const float*)d_in[9],  *nb1 = (const float*)d_in[10];
    const float *nw2 = (const float*)d_in[11], *nb2 = (const float*)d_in[12];
    const float *nw3 = (const float*)d_in[13], *nb3 = (const float*)d_in[14];
    const float *dw1 = (const float*)d_in[15], *db1 = (const float*)d_in[16];
    const float *dw2 = (const float*)d_in[17], *db2 = (const float*)d_in[18];
    const float *dw3 = (const float*)d_in[19], *db3 = (const float*)d_in[20];
    const float *dw4 = (const float*)d_in[21], *db4 = (const float*)d_in[22];
    float* out = (float*)d_out;

    char* p = (char*)d_ws;
    auto carve = [&](size_t bytes) {
        char* r = p;
        p += (bytes + 255) & ~(size_t)255;
        return r;
    };
    int2*   sd      = (int2*)  carve(sizeof(int2)   * N_EDGES);
    float4* dnrm    = (float4*)carve(sizeof(float4) * N_EDGES);
    float4* ea      = (float4*)carve(sizeof(float4) * N_EDGES);
    int2*   staging = (int2*)  carve(sizeof(int2)   * SCAN_NB * MAXB);
    float4* px4     = (float4*)carve(sizeof(float4) * N_NODES);
    float*  f       = (float*) carve(sizeof(float)  * N_NODES);
    int*    rowptr  = (int*)   carve(sizeof(int)    * (N_NODES + 1));
    int*    btail   = (int*)   carve(sizeof(int)    * 256);
    int*    bbase   = (int*)   carve(sizeof(int)    * 256);
    char*   eimg    = (char*)  carve(EIMG_B);
    char*   nimg    = (char*)  carve(EIMG_B);
    char*   dimg    = (char*)  carve(DIMG_B);

    const int nb_n  = SCAN_NB;                 // 196
    const int nb_e  = (N_EDGES + 255) / 256;   // 3125, exact
    const int nb_e64 = N_EDGES / 64;           // 12500, exact
    const int nb_b  = (N_EDGES + 2047) / 2048; // 391

    hipMemsetAsync(btail, 0, sizeof(int) * 256, stream);
    k_node_init<<<nb_n, 256, 0, stream>>>(X, yp, px4, f);
    k_prep<<<3, 256, 0, stream>>>(ew1, ew2, ew3, eb1, eb2, eb3,
                                  nw1, nw2, nw3, nb1, nb2, nb3,
                                  dw1, dw2, dw3, dw4, db1, db2, db3, db4,
                                  eimg, nimg, dimg);
    k_bucket<<<nb_b, 256, 0, stream>>>(edge, btail, staging);
    k_bscan<<<1, 256, 0, stream>>>(btail, bbase);
    k_bsort<<<nb_n, 256, 0, stream>>>(staging, btail, bbase, sd, rowptr);
    k_edge_init<<<nb_e, 256, 0, stream>>>(sd, px4, yp, dnrm, ea);

    for (int it = 0; it < 3; ++it) {
        k_edge_mlp<<<nb_e64, 64, 0, stream>>>(sd, dnrm, ea, f, eimg);
        k_node_mlp<<<nb_n, 256, 0, stream>>>(px4, f, ea, rowptr, nimg);
    }
    k_decoder<<<nb_n, 256, 0, stream>>>(px4, f, yp, dimg, out);
}

// Round 18
// 268.111 us; speedup vs baseline: 1.1018x; 1.0071x over previous
//
#include <hip/hip_runtime.h>
#include <math.h>

#define N_NODES 50000
#define N_EDGES 800000
#define EPS 1e-12f
#define SCAN_NB 196   // ceil(50000/256) node blocks; also bucket count (dst>>8)
#define MAXB 6144     // per-bucket capacity (mean 4082)

typedef __attribute__((ext_vector_type(8))) short bf16x8;
typedef __attribute__((ext_vector_type(4))) float f32x4;

__device__ inline unsigned pk_bf16(float a, float b) {
    unsigned ua = __float_as_uint(a), ub = __float_as_uint(b);
    ua = (ua + 0x7FFFu + ((ua >> 16) & 1u)) >> 16;
    ub = (ub + 0x7FFFu + ((ub >> 16) & 1u)) >> 16;
    return ua | (ub << 16);
}

// image layouts (weights bf16 + biases fp32)
#define W1OFF 0
#define W2OFF 4096
#define W3OFF 13312
#define RS 144
#define EB1 15616
#define EB2 15872
#define EB3 16128
#define EIMG_B 16192     // also NIMG_B
#define DW1OFF 0
#define DW2OFF 4096
#define DW3OFF 13312
#define DW4OFF 22528
#define DB1 24832
#define DB2 25088
#define DB3 25344
#define DB4 25600
#define DIMG_B 25664

// ---------------- K0: per-node precompute ----------------
__global__ void k_node_init(const float* __restrict__ X, const float* __restrict__ yp,
                            float4* __restrict__ px4, float* __restrict__ f) {
    int n = blockIdx.x * blockDim.x + threadIdx.x;
    if (n < N_NODES) {
        px4[n] = make_float4(X[n * 6 + 0], X[n * 6 + 1], X[n * 6 + 2], X[n * 6 + 4]);
        f[n] = yp[n];
    }
}

// ---------------- KP: one-shot bf16 weight-image + fp32 bias prep -----------
__global__ __launch_bounds__(256) void k_prep(
    const float* __restrict__ ew1, const float* __restrict__ ew2,
    const float* __restrict__ ew3, const float* __restrict__ eb1,
    const float* __restrict__ eb2, const float* __restrict__ eb3,
    const float* __restrict__ nw1, const float* __restrict__ nw2,
    const float* __restrict__ nw3, const float* __restrict__ nb1,
    const float* __restrict__ nb2, const float* __restrict__ nb3,
    const float* __restrict__ dw1, const float* __restrict__ dw2,
    const float* __restrict__ dw3, const float* __restrict__ dw4,
    const float* __restrict__ db1, const float* __restrict__ db2,
    const float* __restrict__ db3, const float* __restrict__ db4,
    char* __restrict__ eimg, char* __restrict__ nimg, char* __restrict__ dimg) {
    const int t = threadIdx.x;
    const int n = t & 63, kg = t >> 6;
    const int n3 = t & 15, kg3 = t >> 4;
    if (blockIdx.x == 0) {
        unsigned pk[4];
#pragma unroll
        for (int i = 0; i < 4; i++) {
            int k0 = kg * 8 + i * 2;
            float v0 = (k0 < 9) ? ew1[k0 * 64 + n] : 0.f;
            float v1 = (k0 + 1 < 9) ? ew1[(k0 + 1) * 64 + n] : 0.f;
            pk[i] = pk_bf16(v0, v1);
        }
        *(uint4*)(eimg + W1OFF + n * 64 + kg * 16) = make_uint4(pk[0], pk[1], pk[2], pk[3]);
        unsigned pk2[8];
#pragma unroll
        for (int i = 0; i < 8; i++) {
            int k0 = kg * 16 + i * 2;
            pk2[i] = pk_bf16(ew2[k0 * 64 + n], ew2[(k0 + 1) * 64 + n]);
        }
        *(uint4*)(eimg + W2OFF + n * RS + kg * 32) = make_uint4(pk2[0], pk2[1], pk2[2], pk2[3]);
        *(uint4*)(eimg + W2OFF + n * RS + kg * 32 + 16) = make_uint4(pk2[4], pk2[5], pk2[6], pk2[7]);
        unsigned pk3[2];
#pragma unroll
        for (int i = 0; i < 2; i++) {
            int k0 = kg3 * 4 + i * 2;
            float v0 = (n3 < 3) ? ew3[k0 * 3 + n3] : 0.f;
            float v1 = (n3 < 3) ? ew3[(k0 + 1) * 3 + n3] : 0.f;
            pk3[i] = pk_bf16(v0, v1);
        }
        *(uint2*)(eimg + W3OFF + n3 * RS + kg3 * 8) = make_uint2(pk3[0], pk3[1]);
        if (t < 64) {
            ((float*)(eimg + EB1))[t] = eb1[t];
            ((float*)(eimg + EB2))[t] = eb2[t];
        }
        if (t < 16) ((float*)(eimg + EB3))[t] = (t < 3) ? eb3[t] : 0.f;
    } else if (blockIdx.x == 1) {
        unsigned pk[4];
#pragma unroll
        for (int i = 0; i < 4; i++) {
            int k0 = kg * 8 + i * 2;
            float v0 = (k0 < 5) ? nw1[k0 * 64 + n] : 0.f;
            float v1 = (k0 + 1 < 5) ? nw1[(k0 + 1) * 64 + n] : 0.f;
            pk[i] = pk_bf16(v0, v1);
        }
        *(uint4*)(nimg + W1OFF + n * 64 + kg * 16) = make_uint4(pk[0], pk[1], pk[2], pk[3]);
        unsigned pk2[8];
#pragma unroll
        for (int i = 0; i < 8; i++) {
            int k0 = kg * 16 + i * 2;
            pk2[i] = pk_bf16(nw2[k0 * 64 + n], nw2[(k0 + 1) * 64 + n]);
        }
        *(uint4*)(nimg + W2OFF + n * RS + kg * 32) = make_uint4(pk2[0], pk2[1], pk2[2], pk2[3]);
        *(uint4*)(nimg + W2OFF + n * RS + kg * 32 + 16) = make_uint4(pk2[4], pk2[5], pk2[6], pk2[7]);
        unsigned pk3[2];
#pragma unroll
        for (int i = 0; i < 2; i++) {
            int k0 = kg3 * 4 + i * 2;
            float v0 = (n3 == 0) ? nw3[k0] : 0.f;
            float v1 = (n3 == 0) ? nw3[k0 + 1] : 0.f;
            pk3[i] = pk_bf16(v0, v1);
        }
        *(uint2*)(nimg + W3OFF + n3 * RS + kg3 * 8) = make_uint2(pk3[0], pk3[1]);
        if (t < 64) {
            ((float*)(nimg + EB1))[t] = nb1[t];
            ((float*)(nimg + EB2))[t] = nb2[t];
        }
        if (t < 16) ((float*)(nimg + EB3))[t] = (t == 0) ? nb3[0] : 0.f;
    } else {
        unsigned pk[4];
#pragma unroll
        for (int i = 0; i < 4; i++) {
            int k0 = kg * 8 + i * 2;
            float v0 = (k0 < 5) ? dw1[k0 * 64 + n] : 0.f;
            float v1 = (k0 + 1 < 5) ? dw1[(k0 + 1) * 64 + n] : 0.f;
            pk[i] = pk_bf16(v0, v1);
        }
        *(uint4*)(dimg + DW1OFF + n * 64 + kg * 16) = make_uint4(pk[0], pk[1], pk[2], pk[3]);
        unsigned pk2[8], pk3b[8];
#pragma unroll
        for (int i = 0; i < 8; i++) {
            int k0 = kg * 16 + i * 2;
            pk2[i] = pk_bf16(dw2[k0 * 64 + n], dw2[(k0 + 1) * 64 + n]);
            pk3b[i] = pk_bf16(dw3[k0 * 64 + n], dw3[(k0 + 1) * 64 + n]);
        }
        *(uint4*)(dimg + DW2OFF + n * RS + kg * 32) = make_uint4(pk2[0], pk2[1], pk2[2], pk2[3]);
        *(uint4*)(dimg + DW2OFF + n * RS + kg * 32 + 16) = make_uint4(pk2[4], pk2[5], pk2[6], pk2[7]);
        *(uint4*)(dimg + DW3OFF + n * RS + kg * 32) = make_uint4(pk3b[0], pk3b[1], pk3b[2], pk3b[3]);
        *(uint4*)(dimg + DW3OFF + n * RS + kg * 32 + 16) = make_uint4(pk3b[4], pk3b[5], pk3b[6], pk3b[7]);
        unsigned pk4[2];
#pragma unroll
        for (int i = 0; i < 2; i++) {
            int k0 = kg3 * 4 + i * 2;
            float v0 = (n3 == 0) ? dw4[k0] : 0.f;
            float v1 = (n3 == 0) ? dw4[k0 + 1] : 0.f;
            pk4[i] = pk_bf16(v0, v1);
        }
        *(uint2*)(dimg + DW4OFF + n3 * RS + kg3 * 8) = make_uint2(pk4[0], pk4[1]);
        if (t < 64) {
            ((float*)(dimg + DB1))[t] = db1[t];
            ((float*)(dimg + DB2))[t] = db2[t];
            ((float*)(dimg + DB3))[t] = db3[t];
        }
        if (t < 16) ((float*)(dimg + DB4))[t] = (t == 0) ? db4[0] : 0.f;
    }
}

// ---------------- S1: coarse bucket (dst>>8) ----------------
__global__ __launch_bounds__(256) void k_bucket(const int* __restrict__ edge,
                                                int* __restrict__ btail,
                                                int2* __restrict__ staging) {
    __shared__ int hist[256], loff[256], gbase[256], fill[256];
    __shared__ int2 ebL[2048];
    __shared__ unsigned short bktL[2048];
    const int t = threadIdx.x;
    const int base = blockIdx.x * 2048;
    const int cnt = min(2048, N_EDGES - base);
    hist[t] = 0; fill[t] = 0;
    __syncthreads();

    int2 my[8]; int mb[8];
#pragma unroll
    for (int j = 0; j < 8; j++) {
        int i = base + t + j * 256;
        if (i < N_EDGES) {
            int s = edge[i], d = edge[N_EDGES + i];
            my[j] = make_int2(s, d);
            mb[j] = d >> 8;
            atomicAdd(&hist[mb[j]], 1);
        } else mb[j] = -1;
    }
    __syncthreads();
    int v = hist[t];
    loff[t] = v;
    __syncthreads();
    for (int off = 1; off < 256; off <<= 1) {
        int x = (t >= off) ? loff[t - off] : 0;
        __syncthreads();
        loff[t] += x;
        __syncthreads();
    }
    int ex = loff[t] - v;
    __syncthreads();
    loff[t] = ex;
    if (v > 0) gbase[t] = atomicAdd(&btail[t], v);
    __syncthreads();
#pragma unroll
    for (int j = 0; j < 8; j++) {
        if (mb[j] >= 0) {
            int lp = loff[mb[j]] + atomicAdd(&fill[mb[j]], 1);
            ebL[lp] = my[j];
            bktL[lp] = (unsigned short)mb[j];
        }
    }
    __syncthreads();
    for (int i = t; i < cnt; i += 256) {
        int b = bktL[i];
        int gp = gbase[b] + (i - loff[b]);
        if (gp < MAXB) staging[b * MAXB + gp] = ebL[i];
    }
}

// ---------------- S2: exclusive scan of bucket sizes ----------------
__global__ void k_bscan(const int* __restrict__ btail, int* __restrict__ bbase) {
    __shared__ int s[256];
    int t = threadIdx.x;
    int v = (t < SCAN_NB) ? btail[t] : 0;
    s[t] = v;
    __syncthreads();
    for (int off = 1; off < 256; off <<= 1) {
        int x = (t >= off) ? s[t - off] : 0;
        __syncthreads();
        s[t] += x;
        __syncthreads();
    }
    if (t < SCAN_NB) bbase[t] = s[t] - v;
}

// ---------------- S3: per-bucket fine sort -> sd + rowptr ----------------
__global__ __launch_bounds__(256) void k_bsort(const int2* __restrict__ staging,
                                               const int* __restrict__ btail,
                                               const int* __restrict__ bbase,
                                               int2* __restrict__ sd,
                                               int* __restrict__ rowptr) {
    __shared__ int hist[256], excl[256], fill[256], sbuf[256];
    __shared__ int2 ebL[MAXB];
    const int b = blockIdx.x, t = threadIdx.x;
    const int size = min(btail[b], MAXB);
    const int gb = bbase[b];
    for (int i = t; i < size; i += 256) ebL[i] = staging[b * MAXB + i];
    hist[t] = 0; fill[t] = 0;
    __syncthreads();
    for (int i = t; i < size; i += 256) atomicAdd(&hist[ebL[i].y & 255], 1);
    __syncthreads();
    int v = hist[t];
    sbuf[t] = v;
    __syncthreads();
    for (int off = 1; off < 256; off <<= 1) {
        int x = (t >= off) ? sbuf[t - off] : 0;
        __syncthreads();
        sbuf[t] += x;
        __syncthreads();
    }
    int ex = sbuf[t] - v;
    excl[t] = ex;
    int n = (b << 8) + t;
    if (n < N_NODES) rowptr[n] = gb + ex;
    if (b == SCAN_NB - 1 && t == 0) rowptr[N_NODES] = N_EDGES;
    __syncthreads();
    for (int i = t; i < size; i += 256) {
        int2 v2 = ebL[i];
        int ld = v2.y & 255;
        int pos = excl[ld] + atomicAdd(&fill[ld], 1);
        sd[gb + pos] = v2;
    }
}

// ---------------- K1: per-edge precompute (sorted order) --------
__global__ void k_edge_init(const int2* __restrict__ sd,
                            const float4* __restrict__ px4,
                            const float* __restrict__ yp,
                            float4* __restrict__ dnrm, float4* __restrict__ ea) {
    int e = blockIdx.x * blockDim.x + threadIdx.x;
    if (e < N_EDGES) {
        int2 SD = sd[e];
        float4 ps = px4[SD.x], pd = px4[SD.y];
        float dx = pd.x - ps.x, dy = pd.y - ps.y, dz = pd.z - ps.z;
        float nrm = sqrtf(dx * dx + dy * dy + dz * dz + EPS);
        dnrm[e] = make_float4(dx, dy, dz, nrm);
        float fr = yp[SD.y] - yp[SD.x];
        ea[e] = make_float4(fr * dx, fr * dy, fr * dz, 0.f);
    }
}

// ---------------- K2: edge MLP, wave-sized blocks (R16 version) -------------
__global__ __launch_bounds__(64, 3) void k_edge_mlp(
    const int2* __restrict__ sd, const float4* __restrict__ dnrm,
    float4* __restrict__ ea, const float* __restrict__ f,
    const char* __restrict__ eimg) {
    __shared__ __align__(16) char mybuf[64 * RS];  // 9.2 KB, one wave
    const int lane = threadIdx.x;
    const int c = lane & 15, q = lane >> 4;

    const int e = blockIdx.x * 64 + lane;
    int2 SD = sd[e];
    float4 DN = dnrm[e];
    float4 EA = ea[e];
    float fs = f[SD.x], fd = f[SD.y];

    bf16x8 Wa1[4], Wa2[8], Wa3[2];
#pragma unroll
    for (int mt = 0; mt < 4; mt++)
        Wa1[mt] = *(const bf16x8*)(eimg + W1OFF + (mt * 16 + c) * 64 + q * 16);
#pragma unroll
    for (int mt = 0; mt < 4; mt++)
#pragma unroll
        for (int ks = 0; ks < 2; ks++)
            Wa2[mt * 2 + ks] =
                *(const bf16x8*)(eimg + W2OFF + (mt * 16 + c) * RS + ks * 64 + q * 16);
#pragma unroll
    for (int ks = 0; ks < 2; ks++)
        Wa3[ks] = *(const bf16x8*)(eimg + W3OFF + c * RS + ks * 64 + q * 16);
    float4 b1v[4], b2v[4], b3v;
#pragma unroll
    for (int mt = 0; mt < 4; mt++) {
        b1v[mt] = *(const float4*)(eimg + EB1 + (mt * 16 + q * 4) * 4);
        b2v[mt] = *(const float4*)(eimg + EB2 + (mt * 16 + q * 4) * 4);
    }
    b3v = *(const float4*)(eimg + EB3 + q * 16);

    {
        char* row = mybuf + lane * RS;
        *(uint4*)(row) = make_uint4(pk_bf16(DN.x, DN.y), pk_bf16(DN.z, DN.w),
                                    pk_bf16(EA.x, EA.y), pk_bf16(EA.z, fs));
        *(uint4*)(row + 16) = make_uint4(pk_bf16(fd, 0.f), 0u, 0u, 0u);
        *(uint4*)(row + 32) = make_uint4(0u, 0u, 0u, 0u);
        *(uint4*)(row + 48) = make_uint4(0u, 0u, 0u, 0u);
    }
    __syncthreads();

#pragma unroll
    for (int nt = 0; nt < 4; nt++) {
        char* rowb = mybuf + (nt * 16 + c) * RS;
        bf16x8 Eb = *(bf16x8*)(rowb + q * 16);
        f32x4 a1[4];
#pragma unroll
        for (int mt = 0; mt < 4; mt++) {
            a1[mt] = (f32x4){b1v[mt].x, b1v[mt].y, b1v[mt].z, b1v[mt].w};
            a1[mt] = __builtin_amdgcn_mfma_f32_16x16x32_bf16(Wa1[mt], Eb, a1[mt], 0, 0, 0);
        }
#pragma unroll
        for (int mt = 0; mt < 4; mt++)
            *(uint2*)(rowb + mt * 32 + q * 8) = make_uint2(
                pk_bf16(fmaxf(a1[mt][0], 0.f), fmaxf(a1[mt][1], 0.f)),
                pk_bf16(fmaxf(a1[mt][2], 0.f), fmaxf(a1[mt][3], 0.f)));
        bf16x8 H0 = *(bf16x8*)(rowb + q * 16);
        bf16x8 H1 = *(bf16x8*)(rowb + 64 + q * 16);
        f32x4 a2[4];
#pragma unroll
        for (int mt = 0; mt < 4; mt++) {
            a2[mt] = (f32x4){b2v[mt].x, b2v[mt].y, b2v[mt].z, b2v[mt].w};
            a2[mt] = __builtin_amdgcn_mfma_f32_16x16x32_bf16(Wa2[mt * 2 + 0], H0, a2[mt], 0, 0, 0);
            a2[mt] = __builtin_amdgcn_mfma_f32_16x16x32_bf16(Wa2[mt * 2 + 1], H1, a2[mt], 0, 0, 0);
        }
#pragma unroll
        for (int mt = 0; mt < 4; mt++)
            *(uint2*)(rowb + mt * 32 + q * 8) = make_uint2(
                pk_bf16(fmaxf(a2[mt][0], 0.f), fmaxf(a2[mt][1], 0.f)),
                pk_bf16(fmaxf(a2[mt][2], 0.f), fmaxf(a2[mt][3], 0.f)));
        bf16x8 G0 = *(bf16x8*)(rowb + q * 16);
        bf16x8 G1 = *(bf16x8*)(rowb + 64 + q * 16);
        f32x4 a3 = (f32x4){b3v.x, b3v.y, b3v.z, b3v.w};
        a3 = __builtin_amdgcn_mfma_f32_16x16x32_bf16(Wa3[0], G0, a3, 0, 0, 0);
        a3 = __builtin_amdgcn_mfma_f32_16x16x32_bf16(Wa3[1], G1, a3, 0, 0, 0);
        if (q == 0)
            *(float4*)(rowb + 128) = make_float4(a3[0], a3[1], a3[2], a3[3]);
    }
    __syncthreads();

    float4 o = *(float4*)(mybuf + lane * RS + 128);
    ea[e] = make_float4(EA.x + o.x, EA.y + o.y, EA.z + o.z, 0.f);
}

// ---------------- K3: segment-mean + node MLP, wave-sized ----------------
__global__ __launch_bounds__(64, 3) void k_node_mlp(
    const float4* __restrict__ px4, float* __restrict__ f,
    const float4* __restrict__ ea, const int* __restrict__ rowptr,
    const char* __restrict__ nimg) {
    __shared__ __align__(16) char mybuf[64 * RS];
    const int lane = threadIdx.x;
    const int c = lane & 15, q = lane >> 4;

    const int idx = blockIdx.x * 64 + lane;
    const int n = (idx < N_NODES) ? idx : (N_NODES - 1);

    int b0 = rowptr[n], b1 = rowptr[n + 1];
    float a0 = 0.f, a1s = 0.f, a2s = 0.f;
    for (int p = b0; p < b1; p++) {
        float4 v = ea[p];
        a0 += v.x; a1s += v.y; a2s += v.z;
    }
    float inv = 1.0f / fmaxf((float)(b1 - b0), 1.0f);
    float4 P = px4[n];
    float fn = f[n];

    bf16x8 Wa1[4], Wa2[8], Wa3[2];
#pragma unroll
    for (int mt = 0; mt < 4; mt++)
        Wa1[mt] = *(const bf16x8*)(nimg + W1OFF + (mt * 16 + c) * 64 + q * 16);
#pragma unroll
    for (int mt = 0; mt < 4; mt++)
#pragma unroll
        for (int ks = 0; ks < 2; ks++)
            Wa2[mt * 2 + ks] =
                *(const bf16x8*)(nimg + W2OFF + (mt * 16 + c) * RS + ks * 64 + q * 16);
#pragma unroll
    for (int ks = 0; ks < 2; ks++)
        Wa3[ks] = *(const bf16x8*)(nimg + W3OFF + c * RS + ks * 64 + q * 16);
    float4 b1v[4], b2v[4], b3v;
#pragma unroll
    for (int mt = 0; mt < 4; mt++) {
        b1v[mt] = *(const float4*)(nimg + EB1 + (mt * 16 + q * 4) * 4);
        b2v[mt] = *(const float4*)(nimg + EB2 + (mt * 16 + q * 4) * 4);
    }
    b3v = *(const float4*)(nimg + EB3 + q * 16);

    {
        char* row = mybuf + lane * RS;
        *(uint4*)(row) = make_uint4(pk_bf16(P.w, fn), pk_bf16(a0 * inv, a1s * inv),
                                    pk_bf16(a2s * inv, 0.f), 0u);
        *(uint4*)(row + 16) = make_uint4(0u, 0u, 0u, 0u);
        *(uint4*)(row + 32) = make_uint4(0u, 0u, 0u, 0u);
        *(uint4*)(row + 48) = make_uint4(0u, 0u, 0u, 0u);
    }
    __syncthreads();

#pragma unroll
    for (int nt = 0; nt < 4; nt++) {
        char* rowb = mybuf + (nt * 16 + c) * RS;
        bf16x8 Eb = *(bf16x8*)(rowb + q * 16);
        f32x4 a1v[4];
#pragma unroll
        for (int mt = 0; mt < 4; mt++) {
            a1v[mt] = (f32x4){b1v[mt].x, b1v[mt].y, b1v[mt].z, b1v[mt].w};
            a1v[mt] = __builtin_amdgcn_mfma_f32_16x16x32_bf16(Wa1[mt], Eb, a1v[mt], 0, 0, 0);
        }
#pragma unroll
        for (int mt = 0; mt < 4; mt++)
            *(uint2*)(rowb + mt * 32 + q * 8) = make_uint2(
                pk_bf16(fmaxf(a1v[mt][0], 0.f), fmaxf(a1v[mt][1], 0.f)),
                pk_bf16(fmaxf(a1v[mt][2], 0.f), fmaxf(a1v[mt][3], 0.f)));
        bf16x8 H0 = *(bf16x8*)(rowb + q * 16);
        bf16x8 H1 = *(bf16x8*)(rowb + 64 + q * 16);
        f32x4 a2v[4];
#pragma unroll
        for (int mt = 0; mt < 4; mt++) {
            a2v[mt] = (f32x4){b2v[mt].x, b2v[mt].y, b2v[mt].z, b2v[mt].w};
            a2v[mt] = __builtin_amdgcn_mfma_f32_16x16x32_bf16(Wa2[mt * 2 + 0], H0, a2v[mt], 0, 0, 0);
            a2v[mt] = __builtin_amdgcn_mfma_f32_16x16x32_bf16(Wa2[mt * 2 + 1], H1, a2v[mt], 0, 0, 0);
        }
#pragma unroll
        for (int mt = 0; mt < 4; mt++)
            *(uint2*)(rowb + mt * 32 + q * 8) = make_uint2(
                pk_bf16(fmaxf(a2v[mt][0], 0.f), fmaxf(a2v[mt][1], 0.f)),
                pk_bf16(fmaxf(a2v[mt][2], 0.f), fmaxf(a2v[mt][3], 0.f)));
        bf16x8 G0 = *(bf16x8*)(rowb + q * 16);
        bf16x8 G1 = *(bf16x8*)(rowb + 64 + q * 16);
        f32x4 a3 = (f32x4){b3v.x, b3v.y, b3v.z, b3v.w};
        a3 = __builtin_amdgcn_mfma_f32_16x16x32_bf16(Wa3[0], G0, a3, 0, 0, 0);
        a3 = __builtin_amdgcn_mfma_f32_16x16x32_bf16(Wa3[1], G1, a3, 0, 0, 0);
        if (q == 0) *(float*)(rowb + 128) = a3[0];
    }
    __syncthreads();

    float o = *(float*)(mybuf + lane * RS + 128);
    if (idx < N_NODES) f[n] = fn + o;
}

// ---------------- K4: decoder, wave-sized ----------
__global__ __launch_bounds__(64, 2) void k_decoder(
    const float4* __restrict__ px4, const float* __restrict__ f,
    const float* __restrict__ yp, const char* __restrict__ dimg,
    float* __restrict__ out) {
    __shared__ __align__(16) char mybuf[64 * RS];
    const int lane = threadIdx.x;
    const int c = lane & 15, q = lane >> 4;

    const int idx = blockIdx.x * 64 + lane;
    const int n = (idx < N_NODES) ? idx : (N_NODES - 1);
    float4 P = px4[n];
    float fn = f[n];

    bf16x8 Wa1[4], Wa2[8], Wa3[8], Wa4[2];
#pragma unroll
    for (int mt = 0; mt < 4; mt++)
        Wa1[mt] = *(const bf16x8*)(dimg + DW1OFF + (mt * 16 + c) * 64 + q * 16);
#pragma unroll
    for (int mt = 0; mt < 4; mt++)
#pragma unroll
        for (int ks = 0; ks < 2; ks++) {
            Wa2[mt * 2 + ks] =
                *(const bf16x8*)(dimg + DW2OFF + (mt * 16 + c) * RS + ks * 64 + q * 16);
            Wa3[mt * 2 + ks] =
                *(const bf16x8*)(dimg + DW3OFF + (mt * 16 + c) * RS + ks * 64 + q * 16);
        }
#pragma unroll
    for (int ks = 0; ks < 2; ks++)
        Wa4[ks] = *(const bf16x8*)(dimg + DW4OFF + c * RS + ks * 64 + q * 16);
    float4 b1v[4], b2v[4], b3v[4], b4v;
#pragma unroll
    for (int mt = 0; mt < 4; mt++) {
        b1v[mt] = *(const float4*)(dimg + DB1 + (mt * 16 + q * 4) * 4);
        b2v[mt] = *(const float4*)(dimg + DB2 + (mt * 16 + q * 4) * 4);
        b3v[mt] = *(const float4*)(dimg + DB3 + (mt * 16 + q * 4) * 4);
    }
    b4v = *(const float4*)(dimg + DB4 + q * 16);

    {
        char* row = mybuf + lane * RS;
        *(uint4*)(row) = make_uint4(pk_bf16(P.x, P.y), pk_bf16(P.z, P.w),
                                    pk_bf16(fn, 0.f), 0u);
        *(uint4*)(row + 16) = make_uint4(0u, 0u, 0u, 0u);
        *(uint4*)(row + 32) = make_uint4(0u, 0u, 0u, 0u);
        *(uint4*)(row + 48) = make_uint4(0u, 0u, 0u, 0u);
    }
    __syncthreads();

#pragma unroll
    for (int nt = 0; nt < 4; nt++) {
        char* rowb = mybuf + (nt * 16 + c) * RS;
        bf16x8 Eb = *(bf16x8*)(rowb + q * 16);
        f32x4 a1v[4];
#pragma unroll
        for (int mt = 0; mt < 4; mt++) {
            a1v[mt] = (f32x4){b1v[mt].x, b1v[mt].y, b1v[mt].z, b1v[mt].w};
            a1v[mt] = __builtin_amdgcn_mfma_f32_16x16x32_bf16(Wa1[mt], Eb, a1v[mt], 0, 0, 0);
        }
#pragma unroll
        for (int mt = 0; mt < 4; mt++)
            *(uint2*)(rowb + mt * 32 + q * 8) = make_uint2(
                pk_bf16(fmaxf(a1v[mt][0], 0.f), fmaxf(a1v[mt][1], 0.f)),
                pk_bf16(fmaxf(a1v[mt][2], 0.f), fmaxf(a1v[mt][3], 0.f)));
        bf16x8 H0 = *(bf16x8*)(rowb + q * 16);
        bf16x8 H1 = *(bf16x8*)(rowb + 64 + q * 16);
        f32x4 a2v[4];
#pragma unroll
        for (int mt = 0; mt < 4; mt++) {
            a2v[mt] = (f32x4){b2v[mt].x, b2v[mt].y, b2v[mt].z, b2v[mt].w};
            a2v[mt] = __builtin_amdgcn_mfma_f32_16x16x32_bf16(Wa2[mt * 2 + 0], H0, a2v[mt], 0, 0, 0);
            a2v[mt] = __builtin_amdgcn_mfma_f32_16x16x32_bf16(Wa2[mt * 2 + 1], H1, a2v[mt], 0, 0, 0);
        }
#pragma unroll
        for (int mt = 0; mt < 4; mt++)
            *(uint2*)(rowb + mt * 32 + q * 8) = make_uint2(
                pk_bf16(fmaxf(a2v[mt][0], 0.f), fmaxf(a2v[mt][1], 0.f)),
                pk_bf16(fmaxf(a2v[mt][2], 0.f), fmaxf(a2v[mt][3], 0.f)));
        bf16x8 G0 = *(bf16x8*)(rowb + q * 16);
        bf16x8 G1 = *(bf16x8*)(rowb + 64 + q * 16);
        f32x4 a3v[4];
#pragma unroll
        for (int mt = 0; mt < 4; mt++) {
            a3v[mt] = (f32x4){b3v[mt].x, b3v[mt].y, b3v[mt].z, b3v[mt].w};
            a3v[mt] = __builtin_amdgcn_mfma_f32_16x16x32_bf16(Wa3[mt * 2 + 0], G0, a3v[mt], 0, 0, 0);
            a3v[mt] = __builtin_amdgcn_mfma_f32_16x16x32_bf16(Wa3[mt * 2 + 1], G1, a3v[mt], 0, 0, 0);
        }
#pragma unroll
        for (int mt = 0; mt < 4; mt++)
            *(uint2*)(rowb + mt * 32 + q * 8) = make_uint2(
                pk_bf16(fmaxf(a3v[mt][0], 0.f), fmaxf(a3v[mt][1], 0.f)),
                pk_bf16(fmaxf(a3v[mt][2], 0.f), fmaxf(a3v[mt][3], 0.f)));
        bf16x8 F0 = *(bf16x8*)(rowb + q * 16);
        bf16x8 F1 = *(bf16x8*)(rowb + 64 + q * 16);
        f32x4 a4 = (f32x4){b4v.x, b4v.y, b4v.z, b4v.w};
        a4 = __builtin_amdgcn_mfma_f32_16x16x32_bf16(Wa4[0], F0, a4, 0, 0, 0);
        a4 = __builtin_amdgcn_mfma_f32_16x16x32_bf16(Wa4[1], F1, a4, 0, 0, 0);
        if (q == 0) *(float*)(rowb + 128) = a4[0];
    }
    __syncthreads();

    float o = *(float*)(mybuf + lane * RS + 128);
    if (idx < N_NODES) out[n] = yp[n] + o;
}

extern "C" void kernel_launch(void* const* d_in, const int* in_sizes, int n_in,
                              void* d_out, int out_size, void* d_ws, size_t ws_size,
                              hipStream_t stream) {
    const float* X    = (const float*)d_in[0];
    const float* yp   = (const float*)d_in[1];
    const int*   edge = (const int*)d_in[2];
    const float *ew1 = (const float*)d_in[3],  *eb1 = (const float*)d_in[4];
    const float *ew2 = (const float*)d_in[5],  *eb2 = (const float*)d_in[6];
    const float *ew3 = (const float*)d_in[7],  *eb3 = (const float*)d_in[8];
    const float *nw1 = (const float*)d_in[9],  *nb1 = (const float*)d_in[10];
    const float *nw2 = (const float*)d_in[11], *nb2 = (const float*)d_in[12];
    const float *nw3 = (const float*)d_in[13], *nb3 = (const float*)d_in[14];
    const float *dw1 = (const float*)d_in[15], *db1 = (const float*)d_in[16];
    const float *dw2 = (const float*)d_in[17], *db2 = (const float*)d_in[18];
    const float *dw3 = (const float*)d_in[19], *db3 = (const float*)d_in[20];
    const float *dw4 = (const float*)d_in[21], *db4 = (const float*)d_in[22];
    float* out = (float*)d_out;

    char* p = (char*)d_ws;
    auto carve = [&](size_t bytes) {
        char* r = p;
        p += (bytes + 255) & ~(size_t)255;
        return r;
    };
    int2*   sd      = (int2*)  carve(sizeof(int2)   * N_EDGES);
    float4* dnrm    = (float4*)carve(sizeof(float4) * N_EDGES);
    float4* ea      = (float4*)carve(sizeof(float4) * N_EDGES);
    int2*   staging = (int2*)  carve(sizeof(int2)   * SCAN_NB * MAXB);
    float4* px4     = (float4*)carve(sizeof(float4) * N_NODES);
    float*  f       = (float*) carve(sizeof(float)  * N_NODES);
    int*    rowptr  = (int*)   carve(sizeof(int)    * (N_NODES + 1));
    int*    btail   = (int*)   carve(sizeof(int)    * 256);
    int*    bbase   = (int*)   carve(sizeof(int)    * 256);
    char*   eimg    = (char*)  carve(EIMG_B);
    char*   nimg    = (char*)  carve(EIMG_B);
    char*   dimg    = (char*)  carve(DIMG_B);

    const int nb_n   = SCAN_NB;                 // 196
    const int nb_n64 = (N_NODES + 63) / 64;     // 782
    const int nb_e   = (N_EDGES + 255) / 256;   // 3125, exact
    const int nb_e64 = N_EDGES / 64;            // 12500, exact
    const int nb_b   = (N_EDGES + 2047) / 2048; // 391

    hipMemsetAsync(btail, 0, sizeof(int) * 256, stream);
    k_node_init<<<nb_n, 256, 0, stream>>>(X, yp, px4, f);
    k_prep<<<3, 256, 0, stream>>>(ew1, ew2, ew3, eb1, eb2, eb3,
                                  nw1, nw2, nw3, nb1, nb2, nb3,
                                  dw1, dw2, dw3, dw4, db1, db2, db3, db4,
                                  eimg, nimg, dimg);
    k_bucket<<<nb_b, 256, 0, stream>>>(edge, btail, staging);
    k_bscan<<<1, 256, 0, stream>>>(btail, bbase);
    k_bsort<<<nb_n, 256, 0, stream>>>(staging, btail, bbase, sd, rowptr);
    k_edge_init<<<nb_e, 256, 0, stream>>>(sd, px4, yp, dnrm, ea);

    for (int it = 0; it < 3; ++it) {
        k_edge_mlp<<<nb_e64, 64, 0, stream>>>(sd, dnrm, ea, f, eimg);
        k_node_mlp<<<nb_n64, 64, 0, stream>>>(px4, f, ea, rowptr, nimg);
    }
    k_decoder<<<nb_n64, 64, 0, stream>>>(px4, f, yp, dimg, out);
}